// Round 14
// baseline (297.134 us; speedup 1.0000x reference)
//
#include <hip/hip_runtime.h>
#include <hip/hip_bf16.h>
#include <hip/hip_fp16.h>

#define NF   64
#define NH   8
#define ND   8
#define NHID 32
#define XS   68   // LDS row stride in shorts (136B: 8B-aligned, 2-way banks at worst)
#define OS   10   // sOut row stride in halves (20B -> conflict-free u32 reads)

typedef __attribute__((ext_vector_type(8))) short bf16x8v;
typedef __attribute__((ext_vector_type(4))) float f32x4v;

__device__ __forceinline__ float bf2f(unsigned short u) {
    union { unsigned int i; float f; } v; v.i = ((unsigned int)u) << 16; return v.f;
}
__device__ __forceinline__ unsigned short f2bf(float f) {
    __hip_bfloat16 b = __float2bfloat16(f);
    union { __hip_bfloat16 b; unsigned short u; } v; v.b = b; return v.u;
}
__device__ __forceinline__ void unpack8(uint4 u, float* o) {
    o[0] = __uint_as_float(u.x << 16); o[1] = __uint_as_float(u.x & 0xffff0000u);
    o[2] = __uint_as_float(u.y << 16); o[3] = __uint_as_float(u.y & 0xffff0000u);
    o[4] = __uint_as_float(u.z << 16); o[5] = __uint_as_float(u.z & 0xffff0000u);
    o[6] = __uint_as_float(u.w << 16); o[7] = __uint_as_float(u.w & 0xffff0000u);
}
__device__ __forceinline__ uint4 pack8(const float* f) {
    uint4 u;
    u.x = (unsigned)f2bf(f[0]) | ((unsigned)f2bf(f[1]) << 16);
    u.y = (unsigned)f2bf(f[2]) | ((unsigned)f2bf(f[3]) << 16);
    u.z = (unsigned)f2bf(f[4]) | ((unsigned)f2bf(f[5]) << 16);
    u.w = (unsigned)f2bf(f[6]) | ((unsigned)f2bf(f[7]) << 16);
    return u;
}
__device__ __forceinline__ float leaky(float x) { return fmaxf(x, 0.2f * x); }
__device__ __forceinline__ float sigmoidf(float x) { return 1.f / (1.f + __expf(-x)); }

__global__ void detect_kernel(const int* __restrict__ edge, int* __restrict__ flags) {
    if (threadIdx.x == 0 && blockIdx.x == 0) {
        int oddnz = 0;
        for (int i = 0; i < 32; i++) oddnz |= edge[2 * i + 1];
        flags[0] = (oddnz == 0) ? 1 : 0;
    }
}

__device__ __forceinline__ void load_edge(const int* __restrict__ edge, int e, int E,
                                          int wide, int& s, int& d) {
    if (wide) { s = edge[2 * e]; d = edge[2 * (E + e)]; }
    else      { s = edge[e];     d = edge[E + e]; }
}

// ---------------------------------------------------------------------------
// Weight prep: transpose + bf16-cast into ws; also zeroes counts[N].
// Layout (shorts): [0,4096) WsT | [4096,8192) WdT | [8192,10240) W1dT
//                  [10240,12288) W1sT | [12288,12544) W2sT
// ---------------------------------------------------------------------------
#define WBF_TOTAL 12544
__global__ __launch_bounds__(256) void prep_weights_kernel(
    const float* __restrict__ Ws, const float* __restrict__ Wd,
    const float* __restrict__ W1d, const float* __restrict__ W1s,
    const float* __restrict__ W2s, unsigned short* __restrict__ o,
    int* __restrict__ counts, int N)
{
    int i = blockIdx.x * 256 + threadIdx.x;
    if (i < N) counts[i] = 0;
    float v;
    if (i < 4096)        { int j = i;         v = Ws [(j & 63) * 64 + (j >> 6)]; }
    else if (i < 8192)   { int j = i - 4096;  v = Wd [(j & 63) * 64 + (j >> 6)]; }
    else if (i < 10240)  { int j = i - 8192;  v = W1d[(j & 63) * 32 + (j >> 6)]; }
    else if (i < 12288)  { int j = i - 10240; v = W1s[(j & 63) * 32 + (j >> 6)]; }
    else if (i < 12544)  { int j = i - 12288; v = W2s[(j & 31) * 8  + (j >> 5)]; }
    else return;
    o[i] = f2bf(v);
}

// ---------------------------------------------------------------------------
// Node phase via MFMA + fused hist tail (rank-claim atomics overlap MFMA
// of other resident blocks). counts must be pre-zeroed (prep kernel).
// ---------------------------------------------------------------------------
__global__ __launch_bounds__(64) void node_mfma_kernel(
    const float* __restrict__ h,
    const unsigned short* __restrict__ WsT, const float* __restrict__ b_src,
    const unsigned short* __restrict__ WdT, const float* __restrict__ b_dst,
    const unsigned short* __restrict__ W1T, const float* __restrict__ ba1,
    const float* __restrict__ Wa2, const float* __restrict__ ba2,
    unsigned short* __restrict__ g_src_out, unsigned short* __restrict__ g_dst_out,
    float* __restrict__ out,
    const int* __restrict__ edge, const int* __restrict__ flags,
    int* __restrict__ counts, int* __restrict__ rank, int E, int N)
{
    __shared__ __align__(16) unsigned short sX[64 * XS];  // h rows, later hid
    __shared__ __align__(16) unsigned short sY[64 * XS];  // g rows (raw)
    __shared__ float sW2[NHID * NH];
    __shared__ float sb2[NH];

    int lane = threadIdx.x;
    int nsub = lane & 15, quad = lane >> 4;
    int base = blockIdx.x * 64;
    int n = base + lane;
    bool valid = n < N;
    size_t nn = valid ? (size_t)n : (size_t)(N - 1);

    for (int i = lane; i < NHID * NH; i += 64) sW2[i] = Wa2[i];
    if (lane < NH) sb2[lane] = ba2[lane];

    {
        const float4* hv = (const float4*)(h + nn * NF);
        unsigned short* xrow = sX + lane * XS;
        #pragma unroll
        for (int k = 0; k < 8; k++) {
            float4 u0 = hv[2 * k], u1 = hv[2 * k + 1];
            float f[8] = { u0.x, u0.y, u0.z, u0.w, u1.x, u1.y, u1.z, u1.w };
            uint4 p = pack8(f);
            uint2* q = (uint2*)(xrow + k * 8);
            q[0] = make_uint2(p.x, p.y);
            q[1] = make_uint2(p.z, p.w);
        }
    }
    __syncthreads();

    #pragma unroll 1
    for (int m = 0; m < 2; m++) {
        const unsigned short* WT = m ? WdT : WsT;
        const float* bb = m ? b_dst : b_src;
        unsigned short* gout = m ? g_dst_out : g_src_out;

        bf16x8v Bf[2][4];
        #pragma unroll
        for (int ks = 0; ks < 2; ks++)
            #pragma unroll
            for (int nt = 0; nt < 4; nt++) {
                union { uint4 u; bf16x8v v; } u;
                u.u = *(const uint4*)(WT + (nt * 16 + nsub) * 64 + ks * 32 + quad * 8);
                Bf[ks][nt] = u.v;
            }

        f32x4v acc[4][4];
        #pragma unroll
        for (int mt = 0; mt < 4; mt++)
            #pragma unroll
            for (int nt = 0; nt < 4; nt++) {
                f32x4v z = {0.f, 0.f, 0.f, 0.f};
                acc[mt][nt] = z;
            }

        #pragma unroll
        for (int ks = 0; ks < 2; ks++)
            #pragma unroll
            for (int mt = 0; mt < 4; mt++) {
                const unsigned short* ap = sX + (mt * 16 + nsub) * XS + ks * 32 + quad * 8;
                union { uint2 d[2]; bf16x8v v; } ua;
                ua.d[0] = *(const uint2*)ap;
                ua.d[1] = *(const uint2*)(ap + 4);
                #pragma unroll
                for (int nt = 0; nt < 4; nt++)
                    acc[mt][nt] = __builtin_amdgcn_mfma_f32_16x16x32_bf16(
                        ua.v, Bf[ks][nt], acc[mt][nt], 0, 0, 0);
            }

        if (m == 1) __syncthreads();

        #pragma unroll
        for (int nt = 0; nt < 4; nt++) {
            float bv = bb[nt * 16 + nsub];
            #pragma unroll
            for (int mt = 0; mt < 4; mt++)
                #pragma unroll
                for (int r = 0; r < 4; r++)
                    sY[(mt * 16 + quad * 4 + r) * XS + nt * 16 + nsub] =
                        f2bf(acc[mt][nt][r] + bv);
        }
        __syncthreads();

        if (valid) {
            const unsigned short* yrow = sY + lane * XS;
            uint4* gp = (uint4*)(gout + (size_t)n * NF);
            #pragma unroll
            for (int k = 0; k < 8; k++) {
                uint2 a = *(const uint2*)(yrow + k * 8);
                uint2 b = *(const uint2*)(yrow + k * 8 + 4);
                gp[k] = make_uint4(a.x, a.y, b.x, b.y);
            }
        }
    }

    bf16x8v B1f[2][2];
    #pragma unroll
    for (int ks = 0; ks < 2; ks++)
        #pragma unroll
        for (int nt = 0; nt < 2; nt++) {
            union { uint4 u; bf16x8v v; } u;
            u.u = *(const uint4*)(W1T + (nt * 16 + nsub) * 64 + ks * 32 + quad * 8);
            B1f[ks][nt] = u.v;
        }

    f32x4v acc2[4][2];
    #pragma unroll
    for (int mt = 0; mt < 4; mt++)
        #pragma unroll
        for (int nt = 0; nt < 2; nt++) {
            f32x4v z = {0.f, 0.f, 0.f, 0.f};
            acc2[mt][nt] = z;
        }

    #pragma unroll
    for (int ks = 0; ks < 2; ks++)
        #pragma unroll
        for (int mt = 0; mt < 4; mt++) {
            const unsigned short* ap = sY + (mt * 16 + nsub) * XS + ks * 32 + quad * 8;
            uint2 d0 = *(const uint2*)ap;
            uint2 d1 = *(const uint2*)(ap + 4);
            float f[8];
            unpack8(make_uint4(d0.x, d0.y, d1.x, d1.y), f);
            #pragma unroll
            for (int t = 0; t < 8; t++) f[t] = leaky(f[t]);
            uint4 p = pack8(f);
            union { uint4 u; bf16x8v v; } ua; ua.u = p;
            #pragma unroll
            for (int nt = 0; nt < 2; nt++)
                acc2[mt][nt] = __builtin_amdgcn_mfma_f32_16x16x32_bf16(
                    ua.v, B1f[ks][nt], acc2[mt][nt], 0, 0, 0);
        }
    __syncthreads();

    #pragma unroll
    for (int nt = 0; nt < 2; nt++) {
        float b1v = ba1[nt * 16 + nsub];
        #pragma unroll
        for (int mt = 0; mt < 4; mt++)
            #pragma unroll
            for (int r = 0; r < 4; r++)
                sX[(mt * 16 + quad * 4 + r) * XS + nt * 16 + nsub] =
                    f2bf(leaky(acc2[mt][nt][r] + b1v));
    }
    __syncthreads();

    if (valid) {
        float hid[NHID];
        const unsigned short* hrow = sX + lane * XS;
        #pragma unroll
        for (int k = 0; k < 8; k++) {
            uint2 dv = *(const uint2*)(hrow + k * 4);
            hid[k * 4 + 0] = bf2f((unsigned short)(dv.x & 0xffffu));
            hid[k * 4 + 1] = bf2f((unsigned short)(dv.x >> 16));
            hid[k * 4 + 2] = bf2f((unsigned short)(dv.y & 0xffffu));
            hid[k * 4 + 3] = bf2f((unsigned short)(dv.y >> 16));
        }
        float a[NH];
        #pragma unroll
        for (int j = 0; j < NH; j++) a[j] = sb2[j];
        #pragma unroll
        for (int k = 0; k < NHID; k++) {
            float xk = hid[k];
            #pragma unroll
            for (int j = 0; j < NH; j++) a[j] = fmaf(xk, sW2[k * NH + j], a[j]);
        }
        #pragma unroll
        for (int j = 0; j < NH; j++) a[j] = sigmoidf(a[j]);

        const unsigned short* yrow = sY + lane * XS;
        float4* op = (float4*)(out + (size_t)n * NF);
        #pragma unroll
        for (int k = 0; k < 8; k++) {
            uint2 u0 = *(const uint2*)(yrow + k * 8);
            uint2 u1 = *(const uint2*)(yrow + k * 8 + 4);
            float g[8];
            unpack8(make_uint4(u0.x, u0.y, u1.x, u1.y), g);
            float ah0 = a[(k * 8) >> 3];
            op[2 * k]     = make_float4(ah0 * g[0], ah0 * g[1], ah0 * g[2], ah0 * g[3]);
            op[2 * k + 1] = make_float4(ah0 * g[4], ah0 * g[5], ah0 * g[6], ah0 * g[7]);
        }
    }

    // ---- fused hist tail: rank-claim atomics overlap other blocks' MFMA ----
    {
        int wide = flags[0];
        int stride = gridDim.x * 64;
        for (int e = blockIdx.x * 64 + lane; e < E; e += stride) {
            int s, d;
            load_edge(edge, e, E, wide, s, d);
            if ((unsigned)s >= (unsigned)N || (unsigned)d >= (unsigned)N) { rank[e] = -1; continue; }
            rank[e] = atomicAdd(&counts[d], 1);
        }
    }
}

// ---------------------------------------------------------------------------
// Node phase, scalar (fallback tiers only).
// ---------------------------------------------------------------------------
template <bool STORE_G>
__global__ __launch_bounds__(256) void node_kernel_t(
    const float* __restrict__ h,
    const float* __restrict__ W_src, const float* __restrict__ b_src,
    const float* __restrict__ W_dst, const float* __restrict__ b_dst,
    const float* __restrict__ Wa1, const float* __restrict__ ba1,
    const float* __restrict__ Wa2, const float* __restrict__ ba2,
    unsigned short* __restrict__ g_src_out, unsigned short* __restrict__ g_dst_out,
    float* __restrict__ out, int N)
{
    __shared__ __align__(16) float sWs[NF * NF];
    __shared__ __align__(16) float sWd[NF * NF];
    __shared__ __align__(16) float sW1[NF * NHID];
    __shared__ __align__(16) float sW2[NHID * NH];
    __shared__ float sbs[NF], sbd[NF], sb1[NHID], sb2[NH];

    int tid = threadIdx.x;
    for (int i = tid; i < NF * NF; i += 256) { sWs[i] = W_src[i]; sWd[i] = W_dst[i]; }
    for (int i = tid; i < NF * NHID; i += 256) sW1[i] = Wa1[i];
    if (tid < NHID * NH) sW2[tid] = Wa2[tid];
    if (tid < NF) { sbs[tid] = b_src[tid]; sbd[tid] = b_dst[tid]; }
    if (tid < NHID) sb1[tid] = ba1[tid];
    if (tid < NH) sb2[tid] = ba2[tid];
    __syncthreads();

    int n = blockIdx.x * 256 + tid;
    if (n >= N) return;

    float hrow[NF];
    const float4* hv = (const float4*)(h + (size_t)n * NF);
    #pragma unroll
    for (int k = 0; k < 16; k++) {
        float4 u = hv[k];
        hrow[k * 4 + 0] = u.x; hrow[k * 4 + 1] = u.y;
        hrow[k * 4 + 2] = u.z; hrow[k * 4 + 3] = u.w;
    }

    float acc[NF];
    const float4* Wsv = (const float4*)sWs;
    const float4* Wdv = (const float4*)sWd;

    if (STORE_G) {
        #pragma unroll
        for (int j = 0; j < NF; j++) acc[j] = sbs[j];
        for (int i = 0; i < NF; i++) {
            float hi = hrow[i];
            #pragma unroll
            for (int jb = 0; jb < 16; jb++) {
                float4 w = Wsv[i * 16 + jb];
                acc[jb * 4 + 0] = fmaf(hi, w.x, acc[jb * 4 + 0]);
                acc[jb * 4 + 1] = fmaf(hi, w.y, acc[jb * 4 + 1]);
                acc[jb * 4 + 2] = fmaf(hi, w.z, acc[jb * 4 + 2]);
                acc[jb * 4 + 3] = fmaf(hi, w.w, acc[jb * 4 + 3]);
            }
        }
        uint4* gs = (uint4*)(g_src_out + (size_t)n * NF);
        #pragma unroll
        for (int k = 0; k < 8; k++) gs[k] = pack8(acc + k * 8);
    }

    #pragma unroll
    for (int j = 0; j < NF; j++) acc[j] = sbd[j];
    for (int i = 0; i < NF; i++) {
        float hi = hrow[i];
        #pragma unroll
        for (int jb = 0; jb < 16; jb++) {
            float4 w = Wdv[i * 16 + jb];
            acc[jb * 4 + 0] = fmaf(hi, w.x, acc[jb * 4 + 0]);
            acc[jb * 4 + 1] = fmaf(hi, w.y, acc[jb * 4 + 1]);
            acc[jb * 4 + 2] = fmaf(hi, w.z, acc[jb * 4 + 2]);
            acc[jb * 4 + 3] = fmaf(hi, w.w, acc[jb * 4 + 3]);
        }
    }
    if (STORE_G) {
        uint4* gd = (uint4*)(g_dst_out + (size_t)n * NF);
        #pragma unroll
        for (int k = 0; k < 8; k++) gd[k] = pack8(acc + k * 8);
    }

    float hid[NHID];
    #pragma unroll
    for (int j = 0; j < NHID; j++) hid[j] = sb1[j];
    const float4* W1v = (const float4*)sW1;
    for (int i = 0; i < NF; i++) {
        float xi = leaky(acc[i]);
        #pragma unroll
        for (int jb = 0; jb < 8; jb++) {
            float4 w = W1v[i * 8 + jb];
            hid[jb * 4 + 0] = fmaf(xi, w.x, hid[jb * 4 + 0]);
            hid[jb * 4 + 1] = fmaf(xi, w.y, hid[jb * 4 + 1]);
            hid[jb * 4 + 2] = fmaf(xi, w.z, hid[jb * 4 + 2]);
            hid[jb * 4 + 3] = fmaf(xi, w.w, hid[jb * 4 + 3]);
        }
    }
    float a[NH];
    #pragma unroll
    for (int j = 0; j < NH; j++) a[j] = sb2[j];
    #pragma unroll
    for (int k = 0; k < NHID; k++) {
        float xk = leaky(hid[k]);
        #pragma unroll
        for (int j = 0; j < NH; j++) a[j] = fmaf(xk, sW2[k * NH + j], a[j]);
    }
    #pragma unroll
    for (int j = 0; j < NH; j++) a[j] = sigmoidf(a[j]);

    float4* ap = (float4*)(out + (size_t)n * NF);
    #pragma unroll
    for (int k = 0; k < 16; k++) {
        int j = k * 4;
        ap[k] = make_float4(a[(j + 0) >> 3] * acc[j + 0],
                            a[(j + 1) >> 3] * acc[j + 1],
                            a[(j + 2) >> 3] * acc[j + 2],
                            a[(j + 3) >> 3] * acc[j + 3]);
    }
}

// ---------------------------------------------------------------------------
// Hist (fallback tiers don't need it; kept for completeness of sort path
// if node fusion is ever disabled).
// ---------------------------------------------------------------------------
__global__ __launch_bounds__(256) void scan1_kernel(
    const int* __restrict__ counts, int* __restrict__ offsets,
    int* __restrict__ bsums, int N)
{
    __shared__ int lds[256];
    int tid = threadIdx.x;
    int base = blockIdx.x * 2048 + tid * 8;
    int v[8]; int s = 0;
    #pragma unroll
    for (int k = 0; k < 8; k++) { int idx = base + k; int t = (idx < N) ? counts[idx] : 0; v[k] = t; s += t; }
    lds[tid] = s;
    __syncthreads();
    for (int off = 1; off < 256; off <<= 1) {
        int y = (tid >= off) ? lds[tid - off] : 0;
        __syncthreads();
        lds[tid] += y;
        __syncthreads();
    }
    int run = lds[tid] - s;
    #pragma unroll
    for (int k = 0; k < 8; k++) { int idx = base + k; if (idx < N) offsets[idx] = run; run += v[k]; }
    if (tid == 255) bsums[blockIdx.x] = lds[255];
}

__global__ void scan2_kernel(int* __restrict__ bsums, int* __restrict__ offsets, int NB, int N) {
    if (threadIdx.x == 0 && blockIdx.x == 0) {
        int run = 0;
        for (int i = 0; i < NB; i++) { int t = bsums[i]; bsums[i] = run; run += t; }
        offsets[N] = run;
    }
}

__global__ __launch_bounds__(256) void scan3_kernel(
    int* __restrict__ offsets, const int* __restrict__ bsums, int N)
{
    int add = bsums[blockIdx.x];
    int base = blockIdx.x * 2048 + threadIdx.x * 8;
    #pragma unroll
    for (int k = 0; k < 8; k++) { int idx = base + k; if (idx < N) offsets[idx] += add; }
}

// ---------------------------------------------------------------------------
// Scatter (atomic-free, single 4B scattered store): sorted_s[pos] = s.
// ---------------------------------------------------------------------------
__global__ __launch_bounds__(256) void scatter_kernel(
    const int* __restrict__ edge, const int* __restrict__ flags,
    const int* __restrict__ offsets, const int* __restrict__ rank,
    int* __restrict__ sorted_s, int E, int N)
{
    int e = blockIdx.x * 256 + threadIdx.x;
    if (e >= E) return;
    int r = rank[e];
    if (r < 0) return;
    int s, d;
    load_edge(edge, e, E, flags[0], s, d);
    sorted_s[offsets[d] + r] = s;
}

// ---------------------------------------------------------------------------
// Fill per-slot d from CSR offsets (contiguous runs, sequential coverage).
// ---------------------------------------------------------------------------
__global__ __launch_bounds__(256) void fill_d_kernel(
    const int* __restrict__ offsets, int* __restrict__ sorted_d, int N)
{
    int d = blockIdx.x * 256 + threadIdx.x;
    if (d >= N) return;
    int beg = offsets[d], end = offsets[d + 1];
    for (int i = beg; i < end; i++) sorted_d[i] = d;
}

// ---------------------------------------------------------------------------
// Edge MLP, both layers via MFMA; weights from pre-transposed bf16.
// ---------------------------------------------------------------------------
__global__ __launch_bounds__(256) void edge_mlp_mfma_kernel(
    const int* __restrict__ sorted_s, const int* __restrict__ sorted_d,
    const int* __restrict__ total_p,
    const unsigned short* __restrict__ g_src, const unsigned short* __restrict__ g_dst,
    const unsigned short* __restrict__ W1T, const float* __restrict__ ba1,
    const unsigned short* __restrict__ W2T, const float* __restrict__ ba2,
    __half* __restrict__ a_sorted)
{
    __shared__ __align__(16) unsigned short sX[4 * 64 * XS];
    __shared__ __align__(16) __half sOut[4 * 64 * OS];
    __shared__ float sb1[NHID], sb2[NH];

    int tid = threadIdx.x;
    if (tid < NHID) sb1[tid] = ba1[tid];
    if (tid < NH) sb2[tid] = ba2[tid];

    int wave = tid >> 6;
    int lane = tid & 63;
    int nsub = lane & 15;
    int quad = lane >> 4;
    int total = *total_p;
    int i = blockIdx.x * 256 + wave * 64 + lane;
    bool valid = i < total;
    int s = valid ? sorted_s[i] : 0;
    int d = valid ? sorted_d[i] : 0;

    unsigned short* xrow = sX + (wave * 64 + lane) * XS;
    {
        const uint4* gs = (const uint4*)(g_src + (size_t)s * NF);
        const uint4* gd = (const uint4*)(g_dst + (size_t)d * NF);
        #pragma unroll
        for (int k = 0; k < 8; k++) {
            float A8[8], B8[8], x8[8];
            unpack8(gs[k], A8); unpack8(gd[k], B8);
            #pragma unroll
            for (int t = 0; t < 8; t++) x8[t] = leaky(A8[t] + B8[t]);
            uint4 pk = pack8(x8);
            uint2* q = (uint2*)(xrow + k * 8);
            q[0] = make_uint2(pk.x, pk.y);
            q[1] = make_uint2(pk.z, pk.w);
        }
    }

    bf16x8v Bf[2][2];
    #pragma unroll
    for (int ks = 0; ks < 2; ks++)
        #pragma unroll
        for (int nt = 0; nt < 2; nt++) {
            union { uint4 u; bf16x8v v; } u;
            u.u = *(const uint4*)(W1T + (nt * 16 + nsub) * 64 + ks * 32 + quad * 8);
            Bf[ks][nt] = u.v;
        }
    bf16x8v B2f;
    {
        union { uint4 u; bf16x8v v; } u;
        if (nsub < NH) u.u = *(const uint4*)(W2T + nsub * 32 + quad * 8);
        else           u.u = make_uint4(0u, 0u, 0u, 0u);
        B2f = u.v;
    }

    __syncthreads();

    f32x4v acc[4][2];
    #pragma unroll
    for (int mt = 0; mt < 4; mt++)
        #pragma unroll
        for (int nt = 0; nt < 2; nt++) {
            f32x4v z = {0.f, 0.f, 0.f, 0.f};
            acc[mt][nt] = z;
        }

    const unsigned short* wbase = sX + wave * 64 * XS;
    #pragma unroll
    for (int ks = 0; ks < 2; ks++) {
        #pragma unroll
        for (int mt = 0; mt < 4; mt++) {
            const unsigned short* ap = wbase + (mt * 16 + nsub) * XS + ks * 32 + quad * 8;
            union { uint2 d[2]; bf16x8v v; } ua;
            ua.d[0] = *(const uint2*)ap;
            ua.d[1] = *(const uint2*)(ap + 4);
            #pragma unroll
            for (int nt = 0; nt < 2; nt++)
                acc[mt][nt] = __builtin_amdgcn_mfma_f32_16x16x32_bf16(
                    ua.v, Bf[ks][nt], acc[mt][nt], 0, 0, 0);
        }
    }

    __syncthreads();

    #pragma unroll
    for (int nt = 0; nt < 2; nt++) {
        int n = nt * 16 + nsub;
        float b1v = sb1[n];
        #pragma unroll
        for (int mt = 0; mt < 4; mt++) {
            #pragma unroll
            for (int r = 0; r < 4; r++) {
                int m = mt * 16 + quad * 4 + r;
                sX[(wave * 64 + m) * XS + n] = f2bf(leaky(acc[mt][nt][r] + b1v));
            }
        }
    }

    __syncthreads();

    f32x4v acc2[4];
    #pragma unroll
    for (int mt = 0; mt < 4; mt++) { f32x4v z = {0.f, 0.f, 0.f, 0.f}; acc2[mt] = z; }
    #pragma unroll
    for (int mt = 0; mt < 4; mt++) {
        const unsigned short* ap = wbase + (mt * 16 + nsub) * XS + quad * 8;
        union { uint2 d[2]; bf16x8v v; } ua;
        ua.d[0] = *(const uint2*)ap;
        ua.d[1] = *(const uint2*)(ap + 4);
        acc2[mt] = __builtin_amdgcn_mfma_f32_16x16x32_bf16(ua.v, B2f, acc2[mt], 0, 0, 0);
    }

    if (nsub < NH) {
        float b2v = sb2[nsub];
        #pragma unroll
        for (int mt = 0; mt < 4; mt++)
            #pragma unroll
            for (int r = 0; r < 4; r++) {
                int m = mt * 16 + quad * 4 + r;
                sOut[(wave * 64 + m) * OS + nsub] = __float2half(sigmoidf(acc2[mt][r] + b2v));
            }
    }
    __syncthreads();

    if (valid) {
        const unsigned int* orow = (const unsigned int*)(sOut + (wave * 64 + lane) * OS);
        uint4 pk = make_uint4(orow[0], orow[1], orow[2], orow[3]);
        *(uint4*)(a_sorted + (size_t)i * NH) = pk;
    }
}

// ---------------------------------------------------------------------------
// Aggregate v2 (sorted_s variant).
// ---------------------------------------------------------------------------
__global__ __launch_bounds__(256) void aggregate_kernel(
    const int* __restrict__ offsets, const int* __restrict__ sorted_s,
    const __half* __restrict__ a_sorted, const unsigned short* __restrict__ g_src,
    float* __restrict__ out, int N)
{
    int d = blockIdx.x * 32 + (threadIdx.x >> 3);
    if (d >= N) return;
    int l = threadIdx.x & 7;
    int beg = offsets[d], end = offsets[d + 1];

    float acc[8] = {0.f, 0.f, 0.f, 0.f, 0.f, 0.f, 0.f, 0.f};
    int i = beg;
    for (; i + 2 <= end; i += 2) {
        int s0 = sorted_s[i];
        int s1 = sorted_s[i + 1];
        float av0 = __half2float(a_sorted[(size_t)i * NH + l]);
        float av1 = __half2float(a_sorted[(size_t)(i + 1) * NH + l]);
        uint4 q0 = *(const uint4*)(g_src + (size_t)s0 * NF + l * 8);
        uint4 q1 = *(const uint4*)(g_src + (size_t)s1 * NF + l * 8);
        float f0[8], f1[8];
        unpack8(q0, f0); unpack8(q1, f1);
        #pragma unroll
        for (int t = 0; t < 8; t++) acc[t] = fmaf(av0, f0[t], acc[t]);
        #pragma unroll
        for (int t = 0; t < 8; t++) acc[t] = fmaf(av1, f1[t], acc[t]);
    }
    if (i < end) {
        int s0 = sorted_s[i];
        float av0 = __half2float(a_sorted[(size_t)i * NH + l]);
        uint4 q0 = *(const uint4*)(g_src + (size_t)s0 * NF + l * 8);
        float f0[8]; unpack8(q0, f0);
        #pragma unroll
        for (int t = 0; t < 8; t++) acc[t] = fmaf(av0, f0[t], acc[t]);
    }

    float4* o4 = (float4*)(out + (size_t)d * NF + l * 8);
    float4 v0 = o4[0], v1 = o4[1];
    v0.x += acc[0]; v0.y += acc[1]; v0.z += acc[2]; v0.w += acc[3];
    v1.x += acc[4]; v1.y += acc[5]; v1.z += acc[6]; v1.w += acc[7];
    o4[0] = v0; o4[1] = v1;
}

// ---------------------------------------------------------------------------
// Fallbacks (small ws): R5 atomic edge kernel / fully fused.
// ---------------------------------------------------------------------------
__global__ __launch_bounds__(256) void edge_kernel(
    const int* __restrict__ edge, const int* __restrict__ flags,
    const unsigned short* __restrict__ g_src, const unsigned short* __restrict__ g_dst,
    const float* __restrict__ Wa1, const float* __restrict__ ba1,
    const float* __restrict__ Wa2, const float* __restrict__ ba2,
    float* __restrict__ out, int E, int N)
{
    __shared__ __align__(16) float sW1[NF * NHID];
    __shared__ __align__(16) float sW2[NHID * NH];
    __shared__ float sb1[NHID], sb2[NH];
    int tid = threadIdx.x;
    for (int i = tid; i < NF * NHID; i += 256) sW1[i] = Wa1[i];
    if (tid < NHID * NH) sW2[tid] = Wa2[tid];
    if (tid < NHID) sb1[tid] = ba1[tid];
    if (tid < NH) sb2[tid] = ba2[tid];
    __syncthreads();

    int e = blockIdx.x * 256 + tid;
    if (e >= E) return;
    int s, d;
    load_edge(edge, e, E, flags[0], s, d);
    if ((unsigned)s >= (unsigned)N || (unsigned)d >= (unsigned)N) return;

    float ms[NF];
    float hid[NHID];
    #pragma unroll
    for (int j = 0; j < NHID; j++) hid[j] = sb1[j];

    const uint4* gs = (const uint4*)(g_src + (size_t)s * NF);
    const uint4* gd = (const uint4*)(g_dst + (size_t)d * NF);
    #pragma unroll
    for (int k = 0; k < 8; k++) {
        float a8[8], b8[8];
        unpack8(gs[k], a8);
        unpack8(gd[k], b8);
        #pragma unroll
        for (int t = 0; t < 8; t++) {
            int i = k * 8 + t;
            ms[i] = a8[t];
            float x = leaky(a8[t] + b8[t]);
            #pragma unroll
            for (int j = 0; j < NHID; j++) hid[j] = fmaf(x, sW1[i * NHID + j], hid[j]);
        }
    }

    float a[NH];
    #pragma unroll
    for (int j = 0; j < NH; j++) a[j] = sb2[j];
    #pragma unroll
    for (int k = 0; k < NHID; k++) {
        float xk = leaky(hid[k]);
        #pragma unroll
        for (int j = 0; j < NH; j++) a[j] = fmaf(xk, sW2[k * NH + j], a[j]);
    }

    float* arow = out + (size_t)d * NF;
    #pragma unroll
    for (int hh = 0; hh < NH; hh++) {
        float ah = sigmoidf(a[hh]);
        #pragma unroll
        for (int dd = 0; dd < ND; dd++)
            unsafeAtomicAdd(arow + hh * ND + dd, ah * ms[hh * ND + dd]);
    }
}

__global__ __launch_bounds__(256) void edge_kernel_fused(
    const int* __restrict__ edge, const int* __restrict__ flags,
    const float* __restrict__ h,
    const float* __restrict__ W_src, const float* __restrict__ b_src,
    const float* __restrict__ W_dst, const float* __restrict__ b_dst,
    const float* __restrict__ Wa1, const float* __restrict__ ba1,
    const float* __restrict__ Wa2, const float* __restrict__ ba2,
    float* __restrict__ out, int E, int N)
{
    __shared__ __align__(16) float sWs[NF * NF];
    __shared__ __align__(16) float sWd[NF * NF];
    __shared__ __align__(16) float sW1[NF * NHID];
    __shared__ __align__(16) float sW2[NHID * NH];
    __shared__ float sbs[NF], sbd[NF], sb1[NHID], sb2[NH];
    int tid = threadIdx.x;
    for (int i = tid; i < NF * NF; i += 256) { sWs[i] = W_src[i]; sWd[i] = W_dst[i]; }
    for (int i = tid; i < NF * NHID; i += 256) sW1[i] = Wa1[i];
    if (tid < NHID * NH) sW2[tid] = Wa2[tid];
    if (tid < NF) { sbs[tid] = b_src[tid]; sbd[tid] = b_dst[tid]; }
    if (tid < NHID) sb1[tid] = ba1[tid];
    if (tid < NH) sb2[tid] = ba2[tid];
    __syncthreads();

    int e = blockIdx.x * 256 + tid;
    if (e >= E) return;
    int wide = flags ? flags[0] : 0;
    int s, d;
    load_edge(edge, e, E, wide, s, d);
    if ((unsigned)s >= (unsigned)N || (unsigned)d >= (unsigned)N) return;

    float gsr[NF], msg[NF];
    {
        float hrow[NF];
        #pragma unroll
        for (int i = 0; i < NF; i++) hrow[i] = h[(size_t)s * NF + i];
        #pragma unroll
        for (int j = 0; j < NF; j++) gsr[j] = sbs[j];
        for (int i = 0; i < NF; i++) {
            float hi = hrow[i];
            #pragma unroll
            for (int j = 0; j < NF; j++) gsr[j] = fmaf(hi, sWs[i * NF + j], gsr[j]);
        }
    }
    #pragma unroll
    for (int j = 0; j < NF; j++) msg[j] = gsr[j] + sbd[j];
    for (int i = 0; i < NF; i++) {
        float hi = h[(size_t)d * NF + i];
        #pragma unroll
        for (int j = 0; j < NF; j++) msg[j] = fmaf(hi, sWd[i * NF + j], msg[j]);
    }

    float hid[NHID];
    #pragma unroll
    for (int j = 0; j < NHID; j++) hid[j] = sb1[j];
    for (int i = 0; i < NF; i++) {
        float x = leaky(msg[i]);
        #pragma unroll
        for (int j = 0; j < NHID; j++) hid[j] = fmaf(x, sW1[i * NHID + j], hid[j]);
    }
    float a[NH];
    #pragma unroll
    for (int j = 0; j < NH; j++) a[j] = sb2[j];
    #pragma unroll
    for (int k = 0; k < NHID; k++) {
        float xk = leaky(hid[k]);
        #pragma unroll
        for (int j = 0; j < NH; j++) a[j] = fmaf(xk, sW2[k * NH + j], a[j]);
    }

    float* arow = out + (size_t)d * NF;
    #pragma unroll
    for (int hh = 0; hh < NH; hh++) {
        float ah = sigmoidf(a[hh]);
        #pragma unroll
        for (int dd = 0; dd < ND; dd++)
            unsafeAtomicAdd(arow + hh * ND + dd, ah * gsr[hh * ND + dd]);
    }
}

static inline size_t al256(size_t x) { return (x + 255) & ~(size_t)255; }

extern "C" void kernel_launch(void* const* d_in, const int* in_sizes, int n_in,
                              void* d_out, int out_size, void* d_ws, size_t ws_size,
                              hipStream_t stream) {
    const float* h       = (const float*)d_in[0];
    const float* W_src   = (const float*)d_in[1];
    const float* b_src   = (const float*)d_in[2];
    const float* W_dst   = (const float*)d_in[3];
    const float* b_dst   = (const float*)d_in[4];
    const float* Wa1_src = (const float*)d_in[5];
    const float* ba1_src = (const float*)d_in[6];
    const float* Wa2_src = (const float*)d_in[7];
    const float* ba2_src = (const float*)d_in[8];
    const float* Wa1_dst = (const float*)d_in[9];
    const float* ba1_dst = (const float*)d_in[10];
    const float* Wa2_dst = (const float*)d_in[11];
    const float* ba2_dst = (const float*)d_in[12];
    const int* edge = (const int*)d_in[13];

    int N = in_sizes[0] / NF;
    int E = in_sizes[13] / 2;
    float* out = (float*)d_out;

    int nodeBlocks = (N + 255) / 256;
    int nodeWaves  = (N + 63) / 64;
    int edgeBlocks = (E + 255) / 256;
    int NB1 = (N + 2047) / 2048;
    int prepN = (N > WBF_TOTAL ? N : WBF_TOTAL);

    size_t o_flags  = 0;
    size_t o_wbf    = al256(o_flags + 256);
    size_t o_gsrc   = al256(o_wbf + (size_t)WBF_TOTAL * 2);
    size_t o_gdst   = al256(o_gsrc + (size_t)N * NF * 2);
    size_t o_asort  = al256(o_gdst + (size_t)N * NF * 2);   // E*NH*2 bytes; first E*4 aliased as rank[]
    size_t o_counts = al256(o_asort + (size_t)E * NH * 2);
    size_t o_offs   = al256(o_counts + (size_t)N * 4);
    size_t o_bsums  = al256(o_offs + ((size_t)N + 1) * 4);
    size_t o_sorted = al256(o_bsums + (size_t)NB1 * 4);     // E*4 sorted_s + E*4 sorted_d
    size_t need     = o_sorted + (size_t)E * 8;

    size_t gB = (size_t)N * NF * 2;

    if (ws_size >= need) {
        char* w = (char*)d_ws;
        int*            flags   = (int*)(w + o_flags);
        unsigned short* wbf     = (unsigned short*)(w + o_wbf);
        unsigned short* WsT     = wbf;
        unsigned short* WdT     = wbf + 4096;
        unsigned short* W1dT    = wbf + 8192;
        unsigned short* W1sT    = wbf + 10240;
        unsigned short* W2sT    = wbf + 12288;
        unsigned short* g_src   = (unsigned short*)(w + o_gsrc);
        unsigned short* g_dst   = (unsigned short*)(w + o_gdst);
        __half*         a_sort  = (__half*)(w + o_asort);
        int*            rank    = (int*)(w + o_asort);      // alias: dead before a_sort is born
        int*            counts  = (int*)(w + o_counts);
        int*            offsets = (int*)(w + o_offs);
        int*            bsums   = (int*)(w + o_bsums);
        int*            sorted_s = (int*)(w + o_sorted);
        int*            sorted_d = sorted_s + E;

        detect_kernel<<<1, 1, 0, stream>>>(edge, flags);
        prep_weights_kernel<<<(prepN + 255) / 256, 256, 0, stream>>>(
            W_src, W_dst, Wa1_dst, Wa1_src, Wa2_src, wbf, counts, N);

        node_mfma_kernel<<<nodeWaves, 64, 0, stream>>>(
            h, WsT, b_src, WdT, b_dst,
            W1dT, ba1_dst, Wa2_dst, ba2_dst,
            g_src, g_dst, out,
            edge, flags, counts, rank, E, N);

        scan1_kernel<<<NB1, 256, 0, stream>>>(counts, offsets, bsums, N);
        scan2_kernel<<<1, 1, 0, stream>>>(bsums, offsets, NB1, N);
        scan3_kernel<<<NB1, 256, 0, stream>>>(offsets, bsums, N);

        scatter_kernel<<<edgeBlocks, 256, 0, stream>>>(
            edge, flags, offsets, rank, sorted_s, E, N);

        fill_d_kernel<<<nodeBlocks, 256, 0, stream>>>(offsets, sorted_d, N);

        edge_mlp_mfma_kernel<<<edgeBlocks, 256, 0, stream>>>(
            sorted_s, sorted_d, offsets + N, g_src, g_dst,
            W1sT, ba1_src, W2sT, ba2_src, a_sort);

        aggregate_kernel<<<(N + 31) / 32, 256, 0, stream>>>(
            offsets, sorted_s, a_sort, g_src, out, N);
    } else if (ws_size >= 256 + 2 * gB) {
        int* flags = (int*)d_ws;
        unsigned short* g_src = (unsigned short*)((char*)d_ws + 256);
        unsigned short* g_dst = g_src + (size_t)N * NF;

        detect_kernel<<<1, 1, 0, stream>>>(edge, flags);

        node_kernel_t<true><<<nodeBlocks, 256, 0, stream>>>(
            h, W_src, b_src, W_dst, b_dst,
            Wa1_dst, ba1_dst, Wa2_dst, ba2_dst,
            g_src, g_dst, out, N);

        edge_kernel<<<edgeBlocks, 256, 0, stream>>>(
            edge, flags, g_src, g_dst,
            Wa1_src, ba1_src, Wa2_src, ba2_src,
            out, E, N);
    } else {
        int* flags = (ws_size >= 256) ? (int*)d_ws : nullptr;
        if (flags) detect_kernel<<<1, 1, 0, stream>>>(edge, flags);

        node_kernel_t<false><<<nodeBlocks, 256, 0, stream>>>(
            h, W_src, b_src, W_dst, b_dst,
            Wa1_dst, ba1_dst, Wa2_dst, ba2_dst,
            nullptr, nullptr, out, N);

        edge_kernel_fused<<<edgeBlocks, 256, 0, stream>>>(
            edge, flags, h,
            W_src, b_src, W_dst, b_dst,
            Wa1_src, ba1_src, Wa2_src, ba2_src,
            out, E, N);
    }
}

// Round 15
// 292.109 us; speedup vs baseline: 1.0172x; 1.0172x over previous
//
#include <hip/hip_runtime.h>
#include <hip/hip_bf16.h>
#include <hip/hip_fp16.h>

#define NF   64
#define NH   8
#define ND   8
#define NHID 32
#define XS   68   // LDS row stride in shorts (136B: 8B-aligned, 2-way banks at worst)
#define OS   10   // sOut row stride in halves (20B -> conflict-free u32 reads)

typedef __attribute__((ext_vector_type(8))) short bf16x8v;
typedef __attribute__((ext_vector_type(4))) float f32x4v;

__device__ __forceinline__ float bf2f(unsigned short u) {
    union { unsigned int i; float f; } v; v.i = ((unsigned int)u) << 16; return v.f;
}
__device__ __forceinline__ unsigned short f2bf(float f) {
    __hip_bfloat16 b = __float2bfloat16(f);
    union { __hip_bfloat16 b; unsigned short u; } v; v.b = b; return v.u;
}
__device__ __forceinline__ void unpack8(uint4 u, float* o) {
    o[0] = __uint_as_float(u.x << 16); o[1] = __uint_as_float(u.x & 0xffff0000u);
    o[2] = __uint_as_float(u.y << 16); o[3] = __uint_as_float(u.y & 0xffff0000u);
    o[4] = __uint_as_float(u.z << 16); o[5] = __uint_as_float(u.z & 0xffff0000u);
    o[6] = __uint_as_float(u.w << 16); o[7] = __uint_as_float(u.w & 0xffff0000u);
}
__device__ __forceinline__ uint4 pack8(const float* f) {
    uint4 u;
    u.x = (unsigned)f2bf(f[0]) | ((unsigned)f2bf(f[1]) << 16);
    u.y = (unsigned)f2bf(f[2]) | ((unsigned)f2bf(f[3]) << 16);
    u.z = (unsigned)f2bf(f[4]) | ((unsigned)f2bf(f[5]) << 16);
    u.w = (unsigned)f2bf(f[6]) | ((unsigned)f2bf(f[7]) << 16);
    return u;
}
__device__ __forceinline__ float leaky(float x) { return fmaxf(x, 0.2f * x); }
__device__ __forceinline__ float sigmoidf(float x) { return 1.f / (1.f + __expf(-x)); }

__device__ __forceinline__ void load_edge(const int* __restrict__ edge, int e, int E,
                                          int wide, int& s, int& d) {
    if (wide) { s = edge[2 * e]; d = edge[2 * (E + e)]; }
    else      { s = edge[e];     d = edge[E + e]; }
}

// ---------------------------------------------------------------------------
// Weight prep: transpose + bf16-cast into ws; zeroes counts[N]; block0/thread0
// also performs the edge-width detection (int64 vs int32 storage).
// Layout (shorts): [0,4096) WsT | [4096,8192) WdT | [8192,10240) W1dT
//                  [10240,12288) W1sT | [12288,12544) W2sT
// ---------------------------------------------------------------------------
#define WBF_TOTAL 12544
__global__ __launch_bounds__(256) void prep_weights_kernel(
    const float* __restrict__ Ws, const float* __restrict__ Wd,
    const float* __restrict__ W1d, const float* __restrict__ W1s,
    const float* __restrict__ W2s, unsigned short* __restrict__ o,
    int* __restrict__ counts, int N,
    const int* __restrict__ edge, int* __restrict__ flags)
{
    int i = blockIdx.x * 256 + threadIdx.x;
    if (i == 0) {
        int oddnz = 0;
        for (int k = 0; k < 32; k++) oddnz |= edge[2 * k + 1];
        flags[0] = (oddnz == 0) ? 1 : 0;
    }
    if (i < N) counts[i] = 0;
    float v;
    if (i < 4096)        { int j = i;         v = Ws [(j & 63) * 64 + (j >> 6)]; }
    else if (i < 8192)   { int j = i - 4096;  v = Wd [(j & 63) * 64 + (j >> 6)]; }
    else if (i < 10240)  { int j = i - 8192;  v = W1d[(j & 63) * 32 + (j >> 6)]; }
    else if (i < 12288)  { int j = i - 10240; v = W1s[(j & 63) * 32 + (j >> 6)]; }
    else if (i < 12544)  { int j = i - 12288; v = W2s[(j & 31) * 8  + (j >> 5)]; }
    else return;
    o[i] = f2bf(v);
}

// ---------------------------------------------------------------------------
// Node phase via MFMA (R13-proven form; no hist tail).
// ---------------------------------------------------------------------------
__global__ __launch_bounds__(64) void node_mfma_kernel(
    const float* __restrict__ h,
    const unsigned short* __restrict__ WsT, const float* __restrict__ b_src,
    const unsigned short* __restrict__ WdT, const float* __restrict__ b_dst,
    const unsigned short* __restrict__ W1T, const float* __restrict__ ba1,
    const float* __restrict__ Wa2, const float* __restrict__ ba2,
    unsigned short* __restrict__ g_src_out, unsigned short* __restrict__ g_dst_out,
    float* __restrict__ out, int N)
{
    __shared__ __align__(16) unsigned short sX[64 * XS];  // h rows, later hid
    __shared__ __align__(16) unsigned short sY[64 * XS];  // g rows (raw)
    __shared__ float sW2[NHID * NH];
    __shared__ float sb2[NH];

    int lane = threadIdx.x;
    int nsub = lane & 15, quad = lane >> 4;
    int base = blockIdx.x * 64;
    int n = base + lane;
    bool valid = n < N;
    size_t nn = valid ? (size_t)n : (size_t)(N - 1);

    for (int i = lane; i < NHID * NH; i += 64) sW2[i] = Wa2[i];
    if (lane < NH) sb2[lane] = ba2[lane];

    {
        const float4* hv = (const float4*)(h + nn * NF);
        unsigned short* xrow = sX + lane * XS;
        #pragma unroll
        for (int k = 0; k < 8; k++) {
            float4 u0 = hv[2 * k], u1 = hv[2 * k + 1];
            float f[8] = { u0.x, u0.y, u0.z, u0.w, u1.x, u1.y, u1.z, u1.w };
            uint4 p = pack8(f);
            uint2* q = (uint2*)(xrow + k * 8);
            q[0] = make_uint2(p.x, p.y);
            q[1] = make_uint2(p.z, p.w);
        }
    }
    __syncthreads();

    #pragma unroll 1
    for (int m = 0; m < 2; m++) {
        const unsigned short* WT = m ? WdT : WsT;
        const float* bb = m ? b_dst : b_src;
        unsigned short* gout = m ? g_dst_out : g_src_out;

        bf16x8v Bf[2][4];
        #pragma unroll
        for (int ks = 0; ks < 2; ks++)
            #pragma unroll
            for (int nt = 0; nt < 4; nt++) {
                union { uint4 u; bf16x8v v; } u;
                u.u = *(const uint4*)(WT + (nt * 16 + nsub) * 64 + ks * 32 + quad * 8);
                Bf[ks][nt] = u.v;
            }

        f32x4v acc[4][4];
        #pragma unroll
        for (int mt = 0; mt < 4; mt++)
            #pragma unroll
            for (int nt = 0; nt < 4; nt++) {
                f32x4v z = {0.f, 0.f, 0.f, 0.f};
                acc[mt][nt] = z;
            }

        #pragma unroll
        for (int ks = 0; ks < 2; ks++)
            #pragma unroll
            for (int mt = 0; mt < 4; mt++) {
                const unsigned short* ap = sX + (mt * 16 + nsub) * XS + ks * 32 + quad * 8;
                union { uint2 d[2]; bf16x8v v; } ua;
                ua.d[0] = *(const uint2*)ap;
                ua.d[1] = *(const uint2*)(ap + 4);
                #pragma unroll
                for (int nt = 0; nt < 4; nt++)
                    acc[mt][nt] = __builtin_amdgcn_mfma_f32_16x16x32_bf16(
                        ua.v, Bf[ks][nt], acc[mt][nt], 0, 0, 0);
            }

        if (m == 1) __syncthreads();

        #pragma unroll
        for (int nt = 0; nt < 4; nt++) {
            float bv = bb[nt * 16 + nsub];
            #pragma unroll
            for (int mt = 0; mt < 4; mt++)
                #pragma unroll
                for (int r = 0; r < 4; r++)
                    sY[(mt * 16 + quad * 4 + r) * XS + nt * 16 + nsub] =
                        f2bf(acc[mt][nt][r] + bv);
        }
        __syncthreads();

        if (valid) {
            const unsigned short* yrow = sY + lane * XS;
            uint4* gp = (uint4*)(gout + (size_t)n * NF);
            #pragma unroll
            for (int k = 0; k < 8; k++) {
                uint2 a = *(const uint2*)(yrow + k * 8);
                uint2 b = *(const uint2*)(yrow + k * 8 + 4);
                gp[k] = make_uint4(a.x, a.y, b.x, b.y);
            }
        }
    }

    bf16x8v B1f[2][2];
    #pragma unroll
    for (int ks = 0; ks < 2; ks++)
        #pragma unroll
        for (int nt = 0; nt < 2; nt++) {
            union { uint4 u; bf16x8v v; } u;
            u.u = *(const uint4*)(W1T + (nt * 16 + nsub) * 64 + ks * 32 + quad * 8);
            B1f[ks][nt] = u.v;
        }

    f32x4v acc2[4][2];
    #pragma unroll
    for (int mt = 0; mt < 4; mt++)
        #pragma unroll
        for (int nt = 0; nt < 2; nt++) {
            f32x4v z = {0.f, 0.f, 0.f, 0.f};
            acc2[mt][nt] = z;
        }

    #pragma unroll
    for (int ks = 0; ks < 2; ks++)
        #pragma unroll
        for (int mt = 0; mt < 4; mt++) {
            const unsigned short* ap = sY + (mt * 16 + nsub) * XS + ks * 32 + quad * 8;
            uint2 d0 = *(const uint2*)ap;
            uint2 d1 = *(const uint2*)(ap + 4);
            float f[8];
            unpack8(make_uint4(d0.x, d0.y, d1.x, d1.y), f);
            #pragma unroll
            for (int t = 0; t < 8; t++) f[t] = leaky(f[t]);
            uint4 p = pack8(f);
            union { uint4 u; bf16x8v v; } ua; ua.u = p;
            #pragma unroll
            for (int nt = 0; nt < 2; nt++)
                acc2[mt][nt] = __builtin_amdgcn_mfma_f32_16x16x32_bf16(
                    ua.v, B1f[ks][nt], acc2[mt][nt], 0, 0, 0);
        }
    __syncthreads();

    #pragma unroll
    for (int nt = 0; nt < 2; nt++) {
        float b1v = ba1[nt * 16 + nsub];
        #pragma unroll
        for (int mt = 0; mt < 4; mt++)
            #pragma unroll
            for (int r = 0; r < 4; r++)
                sX[(mt * 16 + quad * 4 + r) * XS + nt * 16 + nsub] =
                    f2bf(leaky(acc2[mt][nt][r] + b1v));
    }
    __syncthreads();

    if (valid) {
        float hid[NHID];
        const unsigned short* hrow = sX + lane * XS;
        #pragma unroll
        for (int k = 0; k < 8; k++) {
            uint2 dv = *(const uint2*)(hrow + k * 4);
            hid[k * 4 + 0] = bf2f((unsigned short)(dv.x & 0xffffu));
            hid[k * 4 + 1] = bf2f((unsigned short)(dv.x >> 16));
            hid[k * 4 + 2] = bf2f((unsigned short)(dv.y & 0xffffu));
            hid[k * 4 + 3] = bf2f((unsigned short)(dv.y >> 16));
        }
        float a[NH];
        #pragma unroll
        for (int j = 0; j < NH; j++) a[j] = sb2[j];
        #pragma unroll
        for (int k = 0; k < NHID; k++) {
            float xk = hid[k];
            #pragma unroll
            for (int j = 0; j < NH; j++) a[j] = fmaf(xk, sW2[k * NH + j], a[j]);
        }
        #pragma unroll
        for (int j = 0; j < NH; j++) a[j] = sigmoidf(a[j]);

        const unsigned short* yrow = sY + lane * XS;
        float4* op = (float4*)(out + (size_t)n * NF);
        #pragma unroll
        for (int k = 0; k < 8; k++) {
            uint2 u0 = *(const uint2*)(yrow + k * 8);
            uint2 u1 = *(const uint2*)(yrow + k * 8 + 4);
            float g[8];
            unpack8(make_uint4(u0.x, u0.y, u1.x, u1.y), g);
            float ah0 = a[(k * 8) >> 3];
            op[2 * k]     = make_float4(ah0 * g[0], ah0 * g[1], ah0 * g[2], ah0 * g[3]);
            op[2 * k + 1] = make_float4(ah0 * g[4], ah0 * g[5], ah0 * g[6], ah0 * g[7]);
        }
    }
}

// ---------------------------------------------------------------------------
// Node phase, scalar (fallback tiers only).
// ---------------------------------------------------------------------------
template <bool STORE_G>
__global__ __launch_bounds__(256) void node_kernel_t(
    const float* __restrict__ h,
    const float* __restrict__ W_src, const float* __restrict__ b_src,
    const float* __restrict__ W_dst, const float* __restrict__ b_dst,
    const float* __restrict__ Wa1, const float* __restrict__ ba1,
    const float* __restrict__ Wa2, const float* __restrict__ ba2,
    unsigned short* __restrict__ g_src_out, unsigned short* __restrict__ g_dst_out,
    float* __restrict__ out, int N)
{
    __shared__ __align__(16) float sWs[NF * NF];
    __shared__ __align__(16) float sWd[NF * NF];
    __shared__ __align__(16) float sW1[NF * NHID];
    __shared__ __align__(16) float sW2[NHID * NH];
    __shared__ float sbs[NF], sbd[NF], sb1[NHID], sb2[NH];

    int tid = threadIdx.x;
    for (int i = tid; i < NF * NF; i += 256) { sWs[i] = W_src[i]; sWd[i] = W_dst[i]; }
    for (int i = tid; i < NF * NHID; i += 256) sW1[i] = Wa1[i];
    if (tid < NHID * NH) sW2[tid] = Wa2[tid];
    if (tid < NF) { sbs[tid] = b_src[tid]; sbd[tid] = b_dst[tid]; }
    if (tid < NHID) sb1[tid] = ba1[tid];
    if (tid < NH) sb2[tid] = ba2[tid];
    __syncthreads();

    int n = blockIdx.x * 256 + tid;
    if (n >= N) return;

    float hrow[NF];
    const float4* hv = (const float4*)(h + (size_t)n * NF);
    #pragma unroll
    for (int k = 0; k < 16; k++) {
        float4 u = hv[k];
        hrow[k * 4 + 0] = u.x; hrow[k * 4 + 1] = u.y;
        hrow[k * 4 + 2] = u.z; hrow[k * 4 + 3] = u.w;
    }

    float acc[NF];
    const float4* Wsv = (const float4*)sWs;
    const float4* Wdv = (const float4*)sWd;

    if (STORE_G) {
        #pragma unroll
        for (int j = 0; j < NF; j++) acc[j] = sbs[j];
        for (int i = 0; i < NF; i++) {
            float hi = hrow[i];
            #pragma unroll
            for (int jb = 0; jb < 16; jb++) {
                float4 w = Wsv[i * 16 + jb];
                acc[jb * 4 + 0] = fmaf(hi, w.x, acc[jb * 4 + 0]);
                acc[jb * 4 + 1] = fmaf(hi, w.y, acc[jb * 4 + 1]);
                acc[jb * 4 + 2] = fmaf(hi, w.z, acc[jb * 4 + 2]);
                acc[jb * 4 + 3] = fmaf(hi, w.w, acc[jb * 4 + 3]);
            }
        }
        uint4* gs = (uint4*)(g_src_out + (size_t)n * NF);
        #pragma unroll
        for (int k = 0; k < 8; k++) gs[k] = pack8(acc + k * 8);
    }

    #pragma unroll
    for (int j = 0; j < NF; j++) acc[j] = sbd[j];
    for (int i = 0; i < NF; i++) {
        float hi = hrow[i];
        #pragma unroll
        for (int jb = 0; jb < 16; jb++) {
            float4 w = Wdv[i * 16 + jb];
            acc[jb * 4 + 0] = fmaf(hi, w.x, acc[jb * 4 + 0]);
            acc[jb * 4 + 1] = fmaf(hi, w.y, acc[jb * 4 + 1]);
            acc[jb * 4 + 2] = fmaf(hi, w.z, acc[jb * 4 + 2]);
            acc[jb * 4 + 3] = fmaf(hi, w.w, acc[jb * 4 + 3]);
        }
    }
    if (STORE_G) {
        uint4* gd = (uint4*)(g_dst_out + (size_t)n * NF);
        #pragma unroll
        for (int k = 0; k < 8; k++) gd[k] = pack8(acc + k * 8);
    }

    float hid[NHID];
    #pragma unroll
    for (int j = 0; j < NHID; j++) hid[j] = sb1[j];
    const float4* W1v = (const float4*)sW1;
    for (int i = 0; i < NF; i++) {
        float xi = leaky(acc[i]);
        #pragma unroll
        for (int jb = 0; jb < 8; jb++) {
            float4 w = W1v[i * 8 + jb];
            hid[jb * 4 + 0] = fmaf(xi, w.x, hid[jb * 4 + 0]);
            hid[jb * 4 + 1] = fmaf(xi, w.y, hid[jb * 4 + 1]);
            hid[jb * 4 + 2] = fmaf(xi, w.z, hid[jb * 4 + 2]);
            hid[jb * 4 + 3] = fmaf(xi, w.w, hid[jb * 4 + 3]);
        }
    }
    float a[NH];
    #pragma unroll
    for (int j = 0; j < NH; j++) a[j] = sb2[j];
    #pragma unroll
    for (int k = 0; k < NHID; k++) {
        float xk = leaky(hid[k]);
        #pragma unroll
        for (int j = 0; j < NH; j++) a[j] = fmaf(xk, sW2[k * NH + j], a[j]);
    }
    #pragma unroll
    for (int j = 0; j < NH; j++) a[j] = sigmoidf(a[j]);

    float4* ap = (float4*)(out + (size_t)n * NF);
    #pragma unroll
    for (int k = 0; k < 16; k++) {
        int j = k * 4;
        ap[k] = make_float4(a[(j + 0) >> 3] * acc[j + 0],
                            a[(j + 1) >> 3] * acc[j + 1],
                            a[(j + 2) >> 3] * acc[j + 2],
                            a[(j + 3) >> 3] * acc[j + 3]);
    }
}

// ---------------------------------------------------------------------------
// Hist + rank claim; 4 independent edges per thread (atomic ILP probe).
// ---------------------------------------------------------------------------
__global__ __launch_bounds__(256) void hist_kernel(
    const int* __restrict__ edge, const int* __restrict__ flags,
    int* __restrict__ counts, int* __restrict__ rank, int E, int N, int T)
{
    int t = blockIdx.x * 256 + threadIdx.x;
    int wide = flags[0];
    #pragma unroll
    for (int k = 0; k < 4; k++) {
        int e = t + k * T;
        if (e >= E) break;
        int s, d;
        load_edge(edge, e, E, wide, s, d);
        if ((unsigned)s >= (unsigned)N || (unsigned)d >= (unsigned)N) { rank[e] = -1; continue; }
        rank[e] = atomicAdd(&counts[d], 1);
    }
}

__global__ __launch_bounds__(256) void scan1_kernel(
    const int* __restrict__ counts, int* __restrict__ offsets,
    int* __restrict__ bsums, int N)
{
    __shared__ int lds[256];
    int tid = threadIdx.x;
    int base = blockIdx.x * 2048 + tid * 8;
    int v[8]; int s = 0;
    #pragma unroll
    for (int k = 0; k < 8; k++) { int idx = base + k; int t = (idx < N) ? counts[idx] : 0; v[k] = t; s += t; }
    lds[tid] = s;
    __syncthreads();
    for (int off = 1; off < 256; off <<= 1) {
        int y = (tid >= off) ? lds[tid - off] : 0;
        __syncthreads();
        lds[tid] += y;
        __syncthreads();
    }
    int run = lds[tid] - s;
    #pragma unroll
    for (int k = 0; k < 8; k++) { int idx = base + k; if (idx < N) offsets[idx] = run; run += v[k]; }
    if (tid == 255) bsums[blockIdx.x] = lds[255];
}

__global__ void scan2_kernel(int* __restrict__ bsums, int* __restrict__ offsets, int NB, int N) {
    if (threadIdx.x == 0 && blockIdx.x == 0) {
        int run = 0;
        for (int i = 0; i < NB; i++) { int t = bsums[i]; bsums[i] = run; run += t; }
        offsets[N] = run;
    }
}

__global__ __launch_bounds__(256) void scan3_kernel(
    int* __restrict__ offsets, const int* __restrict__ bsums, int N)
{
    int add = bsums[blockIdx.x];
    int base = blockIdx.x * 2048 + threadIdx.x * 8;
    #pragma unroll
    for (int k = 0; k < 8; k++) { int idx = base + k; if (idx < N) offsets[idx] += add; }
}

// ---------------------------------------------------------------------------
// Scatter (atomic-free, single 4B scattered store): sorted_s[pos] = s.
// ---------------------------------------------------------------------------
__global__ __launch_bounds__(256) void scatter_kernel(
    const int* __restrict__ edge, const int* __restrict__ flags,
    const int* __restrict__ offsets, const int* __restrict__ rank,
    int* __restrict__ sorted_s, int E, int N)
{
    int e = blockIdx.x * 256 + threadIdx.x;
    if (e >= E) return;
    int r = rank[e];
    if (r < 0) return;
    int s, d;
    load_edge(edge, e, E, flags[0], s, d);
    sorted_s[offsets[d] + r] = s;
}

__global__ __launch_bounds__(256) void fill_d_kernel(
    const int* __restrict__ offsets, int* __restrict__ sorted_d, int N)
{
    int d = blockIdx.x * 256 + threadIdx.x;
    if (d >= N) return;
    int beg = offsets[d], end = offsets[d + 1];
    for (int i = beg; i < end; i++) sorted_d[i] = d;
}

// ---------------------------------------------------------------------------
// Edge MLP, both layers via MFMA; weights from pre-transposed bf16.
// ---------------------------------------------------------------------------
__global__ __launch_bounds__(256) void edge_mlp_mfma_kernel(
    const int* __restrict__ sorted_s, const int* __restrict__ sorted_d,
    const int* __restrict__ total_p,
    const unsigned short* __restrict__ g_src, const unsigned short* __restrict__ g_dst,
    const unsigned short* __restrict__ W1T, const float* __restrict__ ba1,
    const unsigned short* __restrict__ W2T, const float* __restrict__ ba2,
    __half* __restrict__ a_sorted)
{
    __shared__ __align__(16) unsigned short sX[4 * 64 * XS];
    __shared__ __align__(16) __half sOut[4 * 64 * OS];
    __shared__ float sb1[NHID], sb2[NH];

    int tid = threadIdx.x;
    if (tid < NHID) sb1[tid] = ba1[tid];
    if (tid < NH) sb2[tid] = ba2[tid];

    int wave = tid >> 6;
    int lane = tid & 63;
    int nsub = lane & 15;
    int quad = lane >> 4;
    int total = *total_p;
    int i = blockIdx.x * 256 + wave * 64 + lane;
    bool valid = i < total;
    int s = valid ? sorted_s[i] : 0;
    int d = valid ? sorted_d[i] : 0;

    unsigned short* xrow = sX + (wave * 64 + lane) * XS;
    {
        const uint4* gs = (const uint4*)(g_src + (size_t)s * NF);
        const uint4* gd = (const uint4*)(g_dst + (size_t)d * NF);
        #pragma unroll
        for (int k = 0; k < 8; k++) {
            float A8[8], B8[8], x8[8];
            unpack8(gs[k], A8); unpack8(gd[k], B8);
            #pragma unroll
            for (int t = 0; t < 8; t++) x8[t] = leaky(A8[t] + B8[t]);
            uint4 pk = pack8(x8);
            uint2* q = (uint2*)(xrow + k * 8);
            q[0] = make_uint2(pk.x, pk.y);
            q[1] = make_uint2(pk.z, pk.w);
        }
    }

    bf16x8v Bf[2][2];
    #pragma unroll
    for (int ks = 0; ks < 2; ks++)
        #pragma unroll
        for (int nt = 0; nt < 2; nt++) {
            union { uint4 u; bf16x8v v; } u;
            u.u = *(const uint4*)(W1T + (nt * 16 + nsub) * 64 + ks * 32 + quad * 8);
            Bf[ks][nt] = u.v;
        }
    bf16x8v B2f;
    {
        union { uint4 u; bf16x8v v; } u;
        if (nsub < NH) u.u = *(const uint4*)(W2T + nsub * 32 + quad * 8);
        else           u.u = make_uint4(0u, 0u, 0u, 0u);
        B2f = u.v;
    }

    __syncthreads();

    f32x4v acc[4][2];
    #pragma unroll
    for (int mt = 0; mt < 4; mt++)
        #pragma unroll
        for (int nt = 0; nt < 2; nt++) {
            f32x4v z = {0.f, 0.f, 0.f, 0.f};
            acc[mt][nt] = z;
        }

    const unsigned short* wbase = sX + wave * 64 * XS;
    #pragma unroll
    for (int ks = 0; ks < 2; ks++) {
        #pragma unroll
        for (int mt = 0; mt < 4; mt++) {
            const unsigned short* ap = wbase + (mt * 16 + nsub) * XS + ks * 32 + quad * 8;
            union { uint2 d[2]; bf16x8v v; } ua;
            ua.d[0] = *(const uint2*)ap;
            ua.d[1] = *(const uint2*)(ap + 4);
            #pragma unroll
            for (int nt = 0; nt < 2; nt++)
                acc[mt][nt] = __builtin_amdgcn_mfma_f32_16x16x32_bf16(
                    ua.v, Bf[ks][nt], acc[mt][nt], 0, 0, 0);
        }
    }

    __syncthreads();

    #pragma unroll
    for (int nt = 0; nt < 2; nt++) {
        int n = nt * 16 + nsub;
        float b1v = sb1[n];
        #pragma unroll
        for (int mt = 0; mt < 4; mt++) {
            #pragma unroll
            for (int r = 0; r < 4; r++) {
                int m = mt * 16 + quad * 4 + r;
                sX[(wave * 64 + m) * XS + n] = f2bf(leaky(acc[mt][nt][r] + b1v));
            }
        }
    }

    __syncthreads();

    f32x4v acc2[4];
    #pragma unroll
    for (int mt = 0; mt < 4; mt++) { f32x4v z = {0.f, 0.f, 0.f, 0.f}; acc2[mt] = z; }
    #pragma unroll
    for (int mt = 0; mt < 4; mt++) {
        const unsigned short* ap = wbase + (mt * 16 + nsub) * XS + quad * 8;
        union { uint2 d[2]; bf16x8v v; } ua;
        ua.d[0] = *(const uint2*)ap;
        ua.d[1] = *(const uint2*)(ap + 4);
        acc2[mt] = __builtin_amdgcn_mfma_f32_16x16x32_bf16(ua.v, B2f, acc2[mt], 0, 0, 0);
    }

    if (nsub < NH) {
        float b2v = sb2[nsub];
        #pragma unroll
        for (int mt = 0; mt < 4; mt++)
            #pragma unroll
            for (int r = 0; r < 4; r++) {
                int m = mt * 16 + quad * 4 + r;
                sOut[(wave * 64 + m) * OS + nsub] = __float2half(sigmoidf(acc2[mt][r] + b2v));
            }
    }
    __syncthreads();

    if (valid) {
        const unsigned int* orow = (const unsigned int*)(sOut + (wave * 64 + lane) * OS);
        uint4 pk = make_uint4(orow[0], orow[1], orow[2], orow[3]);
        *(uint4*)(a_sorted + (size_t)i * NH) = pk;
    }
}

// ---------------------------------------------------------------------------
// Aggregate v2 (sorted_s variant).
// ---------------------------------------------------------------------------
__global__ __launch_bounds__(256) void aggregate_kernel(
    const int* __restrict__ offsets, const int* __restrict__ sorted_s,
    const __half* __restrict__ a_sorted, const unsigned short* __restrict__ g_src,
    float* __restrict__ out, int N)
{
    int d = blockIdx.x * 32 + (threadIdx.x >> 3);
    if (d >= N) return;
    int l = threadIdx.x & 7;
    int beg = offsets[d], end = offsets[d + 1];

    float acc[8] = {0.f, 0.f, 0.f, 0.f, 0.f, 0.f, 0.f, 0.f};
    int i = beg;
    for (; i + 2 <= end; i += 2) {
        int s0 = sorted_s[i];
        int s1 = sorted_s[i + 1];
        float av0 = __half2float(a_sorted[(size_t)i * NH + l]);
        float av1 = __half2float(a_sorted[(size_t)(i + 1) * NH + l]);
        uint4 q0 = *(const uint4*)(g_src + (size_t)s0 * NF + l * 8);
        uint4 q1 = *(const uint4*)(g_src + (size_t)s1 * NF + l * 8);
        float f0[8], f1[8];
        unpack8(q0, f0); unpack8(q1, f1);
        #pragma unroll
        for (int t = 0; t < 8; t++) acc[t] = fmaf(av0, f0[t], acc[t]);
        #pragma unroll
        for (int t = 0; t < 8; t++) acc[t] = fmaf(av1, f1[t], acc[t]);
    }
    if (i < end) {
        int s0 = sorted_s[i];
        float av0 = __half2float(a_sorted[(size_t)i * NH + l]);
        uint4 q0 = *(const uint4*)(g_src + (size_t)s0 * NF + l * 8);
        float f0[8]; unpack8(q0, f0);
        #pragma unroll
        for (int t = 0; t < 8; t++) acc[t] = fmaf(av0, f0[t], acc[t]);
    }

    float4* o4 = (float4*)(out + (size_t)d * NF + l * 8);
    float4 v0 = o4[0], v1 = o4[1];
    v0.x += acc[0]; v0.y += acc[1]; v0.z += acc[2]; v0.w += acc[3];
    v1.x += acc[4]; v1.y += acc[5]; v1.z += acc[6]; v1.w += acc[7];
    o4[0] = v0; o4[1] = v1;
}

// ---------------------------------------------------------------------------
// Fallbacks (small ws): detect + R5 atomic edge kernel / fully fused.
// ---------------------------------------------------------------------------
__global__ void detect_kernel(const int* __restrict__ edge, int* __restrict__ flags) {
    if (threadIdx.x == 0 && blockIdx.x == 0) {
        int oddnz = 0;
        for (int i = 0; i < 32; i++) oddnz |= edge[2 * i + 1];
        flags[0] = (oddnz == 0) ? 1 : 0;
    }
}

__global__ __launch_bounds__(256) void edge_kernel(
    const int* __restrict__ edge, const int* __restrict__ flags,
    const unsigned short* __restrict__ g_src, const unsigned short* __restrict__ g_dst,
    const float* __restrict__ Wa1, const float* __restrict__ ba1,
    const float* __restrict__ Wa2, const float* __restrict__ ba2,
    float* __restrict__ out, int E, int N)
{
    __shared__ __align__(16) float sW1[NF * NHID];
    __shared__ __align__(16) float sW2[NHID * NH];
    __shared__ float sb1[NHID], sb2[NH];
    int tid = threadIdx.x;
    for (int i = tid; i < NF * NHID; i += 256) sW1[i] = Wa1[i];
    if (tid < NHID * NH) sW2[tid] = Wa2[tid];
    if (tid < NHID) sb1[tid] = ba1[tid];
    if (tid < NH) sb2[tid] = ba2[tid];
    __syncthreads();

    int e = blockIdx.x * 256 + tid;
    if (e >= E) return;
    int s, d;
    load_edge(edge, e, E, flags[0], s, d);
    if ((unsigned)s >= (unsigned)N || (unsigned)d >= (unsigned)N) return;

    float ms[NF];
    float hid[NHID];
    #pragma unroll
    for (int j = 0; j < NHID; j++) hid[j] = sb1[j];

    const uint4* gs = (const uint4*)(g_src + (size_t)s * NF);
    const uint4* gd = (const uint4*)(g_dst + (size_t)d * NF);
    #pragma unroll
    for (int k = 0; k < 8; k++) {
        float a8[8], b8[8];
        unpack8(gs[k], a8);
        unpack8(gd[k], b8);
        #pragma unroll
        for (int t = 0; t < 8; t++) {
            int i = k * 8 + t;
            ms[i] = a8[t];
            float x = leaky(a8[t] + b8[t]);
            #pragma unroll
            for (int j = 0; j < NHID; j++) hid[j] = fmaf(x, sW1[i * NHID + j], hid[j]);
        }
    }

    float a[NH];
    #pragma unroll
    for (int j = 0; j < NH; j++) a[j] = sb2[j];
    #pragma unroll
    for (int k = 0; k < NHID; k++) {
        float xk = leaky(hid[k]);
        #pragma unroll
        for (int j = 0; j < NH; j++) a[j] = fmaf(xk, sW2[k * NH + j], a[j]);
    }

    float* arow = out + (size_t)d * NF;
    #pragma unroll
    for (int hh = 0; hh < NH; hh++) {
        float ah = sigmoidf(a[hh]);
        #pragma unroll
        for (int dd = 0; dd < ND; dd++)
            unsafeAtomicAdd(arow + hh * ND + dd, ah * ms[hh * ND + dd]);
    }
}

__global__ __launch_bounds__(256) void edge_kernel_fused(
    const int* __restrict__ edge, const int* __restrict__ flags,
    const float* __restrict__ h,
    const float* __restrict__ W_src, const float* __restrict__ b_src,
    const float* __restrict__ W_dst, const float* __restrict__ b_dst,
    const float* __restrict__ Wa1, const float* __restrict__ ba1,
    const float* __restrict__ Wa2, const float* __restrict__ ba2,
    float* __restrict__ out, int E, int N)
{
    __shared__ __align__(16) float sWs[NF * NF];
    __shared__ __align__(16) float sWd[NF * NF];
    __shared__ __align__(16) float sW1[NF * NHID];
    __shared__ __align__(16) float sW2[NHID * NH];
    __shared__ float sbs[NF], sbd[NF], sb1[NHID], sb2[NH];
    int tid = threadIdx.x;
    for (int i = tid; i < NF * NF; i += 256) { sWs[i] = W_src[i]; sWd[i] = W_dst[i]; }
    for (int i = tid; i < NF * NHID; i += 256) sW1[i] = Wa1[i];
    if (tid < NHID * NH) sW2[tid] = Wa2[tid];
    if (tid < NF) { sbs[tid] = b_src[tid]; sbd[tid] = b_dst[tid]; }
    if (tid < NHID) sb1[tid] = ba1[tid];
    if (tid < NH) sb2[tid] = ba2[tid];
    __syncthreads();

    int e = blockIdx.x * 256 + tid;
    if (e >= E) return;
    int wide = flags ? flags[0] : 0;
    int s, d;
    load_edge(edge, e, E, wide, s, d);
    if ((unsigned)s >= (unsigned)N || (unsigned)d >= (unsigned)N) return;

    float gsr[NF], msg[NF];
    {
        float hrow[NF];
        #pragma unroll
        for (int i = 0; i < NF; i++) hrow[i] = h[(size_t)s * NF + i];
        #pragma unroll
        for (int j = 0; j < NF; j++) gsr[j] = sbs[j];
        for (int i = 0; i < NF; i++) {
            float hi = hrow[i];
            #pragma unroll
            for (int j = 0; j < NF; j++) gsr[j] = fmaf(hi, sWs[i * NF + j], gsr[j]);
        }
    }
    #pragma unroll
    for (int j = 0; j < NF; j++) msg[j] = gsr[j] + sbd[j];
    for (int i = 0; i < NF; i++) {
        float hi = h[(size_t)d * NF + i];
        #pragma unroll
        for (int j = 0; j < NF; j++) msg[j] = fmaf(hi, sWd[i * NF + j], msg[j]);
    }

    float hid[NHID];
    #pragma unroll
    for (int j = 0; j < NHID; j++) hid[j] = sb1[j];
    for (int i = 0; i < NF; i++) {
        float x = leaky(msg[i]);
        #pragma unroll
        for (int j = 0; j < NHID; j++) hid[j] = fmaf(x, sW1[i * NHID + j], hid[j]);
    }
    float a[NH];
    #pragma unroll
    for (int j = 0; j < NH; j++) a[j] = sb2[j];
    #pragma unroll
    for (int k = 0; k < NHID; k++) {
        float xk = leaky(hid[k]);
        #pragma unroll
        for (int j = 0; j < NH; j++) a[j] = fmaf(xk, sW2[k * NH + j], a[j]);
    }

    float* arow = out + (size_t)d * NF;
    #pragma unroll
    for (int hh = 0; hh < NH; hh++) {
        float ah = sigmoidf(a[hh]);
        #pragma unroll
        for (int dd = 0; dd < ND; dd++)
            unsafeAtomicAdd(arow + hh * ND + dd, ah * gsr[hh * ND + dd]);
    }
}

static inline size_t al256(size_t x) { return (x + 255) & ~(size_t)255; }

extern "C" void kernel_launch(void* const* d_in, const int* in_sizes, int n_in,
                              void* d_out, int out_size, void* d_ws, size_t ws_size,
                              hipStream_t stream) {
    const float* h       = (const float*)d_in[0];
    const float* W_src   = (const float*)d_in[1];
    const float* b_src   = (const float*)d_in[2];
    const float* W_dst   = (const float*)d_in[3];
    const float* b_dst   = (const float*)d_in[4];
    const float* Wa1_src = (const float*)d_in[5];
    const float* ba1_src = (const float*)d_in[6];
    const float* Wa2_src = (const float*)d_in[7];
    const float* ba2_src = (const float*)d_in[8];
    const float* Wa1_dst = (const float*)d_in[9];
    const float* ba1_dst = (const float*)d_in[10];
    const float* Wa2_dst = (const float*)d_in[11];
    const float* ba2_dst = (const float*)d_in[12];
    const int* edge = (const int*)d_in[13];

    int N = in_sizes[0] / NF;
    int E = in_sizes[13] / 2;
    float* out = (float*)d_out;

    int nodeBlocks = (N + 255) / 256;
    int nodeWaves  = (N + 63) / 64;
    int edgeBlocks = (E + 255) / 256;
    int NB1 = (N + 2047) / 2048;
    int prepN = (N > WBF_TOTAL ? N : WBF_TOTAL);
    int histBlocks = (E + 1023) / 1024;
    int histT = histBlocks * 256;

    size_t o_flags  = 0;
    size_t o_wbf    = al256(o_flags + 256);
    size_t o_gsrc   = al256(o_wbf + (size_t)WBF_TOTAL * 2);
    size_t o_gdst   = al256(o_gsrc + (size_t)N * NF * 2);
    size_t o_asort  = al256(o_gdst + (size_t)N * NF * 2);   // E*NH*2 bytes; first E*4 aliased as rank[]
    size_t o_counts = al256(o_asort + (size_t)E * NH * 2);
    size_t o_offs   = al256(o_counts + (size_t)N * 4);
    size_t o_bsums  = al256(o_offs + ((size_t)N + 1) * 4);
    size_t o_sorted = al256(o_bsums + (size_t)NB1 * 4);     // E*4 sorted_s + E*4 sorted_d
    size_t need     = o_sorted + (size_t)E * 8;

    size_t gB = (size_t)N * NF * 2;

    if (ws_size >= need) {
        char* w = (char*)d_ws;
        int*            flags   = (int*)(w + o_flags);
        unsigned short* wbf     = (unsigned short*)(w + o_wbf);
        unsigned short* WsT     = wbf;
        unsigned short* WdT     = wbf + 4096;
        unsigned short* W1dT    = wbf + 8192;
        unsigned short* W1sT    = wbf + 10240;
        unsigned short* W2sT    = wbf + 12288;
        unsigned short* g_src   = (unsigned short*)(w + o_gsrc);
        unsigned short* g_dst   = (unsigned short*)(w + o_gdst);
        __half*         a_sort  = (__half*)(w + o_asort);
        int*            rank    = (int*)(w + o_asort);      // alias: dead before a_sort is born
        int*            counts  = (int*)(w + o_counts);
        int*            offsets = (int*)(w + o_offs);
        int*            bsums   = (int*)(w + o_bsums);
        int*            sorted_s = (int*)(w + o_sorted);
        int*            sorted_d = sorted_s + E;

        prep_weights_kernel<<<(prepN + 255) / 256, 256, 0, stream>>>(
            W_src, W_dst, Wa1_dst, Wa1_src, Wa2_src, wbf, counts, N, edge, flags);

        node_mfma_kernel<<<nodeWaves, 64, 0, stream>>>(
            h, WsT, b_src, WdT, b_dst,
            W1dT, ba1_dst, Wa2_dst, ba2_dst,
            g_src, g_dst, out, N);

        hist_kernel<<<histBlocks, 256, 0, stream>>>(
            edge, flags, counts, rank, E, N, histT);

        scan1_kernel<<<NB1, 256, 0, stream>>>(counts, offsets, bsums, N);
        scan2_kernel<<<1, 1, 0, stream>>>(bsums, offsets, NB1, N);
        scan3_kernel<<<NB1, 256, 0, stream>>>(offsets, bsums, N);

        scatter_kernel<<<edgeBlocks, 256, 0, stream>>>(
            edge, flags, offsets, rank, sorted_s, E, N);

        fill_d_kernel<<<nodeBlocks, 256, 0, stream>>>(offsets, sorted_d, N);

        edge_mlp_mfma_kernel<<<edgeBlocks, 256, 0, stream>>>(
            sorted_s, sorted_d, offsets + N, g_src, g_dst,
            W1sT, ba1_src, W2sT, ba2_src, a_sort);

        aggregate_kernel<<<(N + 31) / 32, 256, 0, stream>>>(
            offsets, sorted_s, a_sort, g_src, out, N);
    } else if (ws_size >= 256 + 2 * gB) {
        int* flags = (int*)d_ws;
        unsigned short* g_src = (unsigned short*)((char*)d_ws + 256);
        unsigned short* g_dst = g_src + (size_t)N * NF;

        detect_kernel<<<1, 1, 0, stream>>>(edge, flags);

        node_kernel_t<true><<<nodeBlocks, 256, 0, stream>>>(
            h, W_src, b_src, W_dst, b_dst,
            Wa1_dst, ba1_dst, Wa2_dst, ba2_dst,
            g_src, g_dst, out, N);

        edge_kernel<<<edgeBlocks, 256, 0, stream>>>(
            edge, flags, g_src, g_dst,
            Wa1_src, ba1_src, Wa2_src, ba2_src,
            out, E, N);
    } else {
        int* flags = (ws_size >= 256) ? (int*)d_ws : nullptr;
        if (flags) detect_kernel<<<1, 1, 0, stream>>>(edge, flags);

        node_kernel_t<false><<<nodeBlocks, 256, 0, stream>>>(
            h, W_src, b_src, W_dst, b_dst,
            Wa1_dst, ba1_dst, Wa2_dst, ba2_dst,
            nullptr, nullptr, out, N);

        edge_kernel_fused<<<edgeBlocks, 256, 0, stream>>>(
            edge, flags, h,
            W_src, b_src, W_dst, b_dst,
            Wa1_src, ba1_src, Wa2_src, ba2_src,
            out, E, N);
    }
}

// Round 16
// 272.251 us; speedup vs baseline: 1.0914x; 1.0729x over previous
//
#include <hip/hip_runtime.h>
#include <hip/hip_bf16.h>
#include <hip/hip_fp16.h>

#define NF   64
#define NH   8
#define ND   8
#define NHID 32
#define XS   68   // LDS row stride in shorts (136B: 8B-aligned, 2-way banks at worst)
#define OS   10   // sOut row stride in halves (20B -> conflict-free u32 reads)

typedef __attribute__((ext_vector_type(8))) short bf16x8v;
typedef __attribute__((ext_vector_type(4))) float f32x4v;

__device__ __forceinline__ float bf2f(unsigned short u) {
    union { unsigned int i; float f; } v; v.i = ((unsigned int)u) << 16; return v.f;
}
__device__ __forceinline__ unsigned short f2bf(float f) {
    __hip_bfloat16 b = __float2bfloat16(f);
    union { __hip_bfloat16 b; unsigned short u; } v; v.b = b; return v.u;
}
__device__ __forceinline__ void unpack8(uint4 u, float* o) {
    o[0] = __uint_as_float(u.x << 16); o[1] = __uint_as_float(u.x & 0xffff0000u);
    o[2] = __uint_as_float(u.y << 16); o[3] = __uint_as_float(u.y & 0xffff0000u);
    o[4] = __uint_as_float(u.z << 16); o[5] = __uint_as_float(u.z & 0xffff0000u);
    o[6] = __uint_as_float(u.w << 16); o[7] = __uint_as_float(u.w & 0xffff0000u);
}
__device__ __forceinline__ uint4 pack8(const float* f) {
    uint4 u;
    u.x = (unsigned)f2bf(f[0]) | ((unsigned)f2bf(f[1]) << 16);
    u.y = (unsigned)f2bf(f[2]) | ((unsigned)f2bf(f[3]) << 16);
    u.z = (unsigned)f2bf(f[4]) | ((unsigned)f2bf(f[5]) << 16);
    u.w = (unsigned)f2bf(f[6]) | ((unsigned)f2bf(f[7]) << 16);
    return u;
}
__device__ __forceinline__ float leaky(float x) { return fmaxf(x, 0.2f * x); }
__device__ __forceinline__ float sigmoidf(float x) { return 1.f / (1.f + __expf(-x)); }

__device__ __forceinline__ void load_edge(const int* __restrict__ edge, int e, int E,
                                          int wide, int& s, int& d) {
    if (wide) { s = edge[2 * e]; d = edge[2 * (E + e)]; }
    else      { s = edge[e];     d = edge[E + e]; }
}

// ---------------------------------------------------------------------------
// Weight prep: transpose + bf16-cast into ws; zeroes counts[N]; thread 0 also
// performs edge-width detection.
// ---------------------------------------------------------------------------
#define WBF_TOTAL 12544
__global__ __launch_bounds__(256) void prep_weights_kernel(
    const float* __restrict__ Ws, const float* __restrict__ Wd,
    const float* __restrict__ W1d, const float* __restrict__ W1s,
    const float* __restrict__ W2s, unsigned short* __restrict__ o,
    int* __restrict__ counts, int N,
    const int* __restrict__ edge, int* __restrict__ flags)
{
    int i = blockIdx.x * 256 + threadIdx.x;
    if (i == 0) {
        int oddnz = 0;
        for (int k = 0; k < 32; k++) oddnz |= edge[2 * k + 1];
        flags[0] = (oddnz == 0) ? 1 : 0;
    }
    if (i < N) counts[i] = 0;
    float v;
    if (i < 4096)        { int j = i;         v = Ws [(j & 63) * 64 + (j >> 6)]; }
    else if (i < 8192)   { int j = i - 4096;  v = Wd [(j & 63) * 64 + (j >> 6)]; }
    else if (i < 10240)  { int j = i - 8192;  v = W1d[(j & 63) * 32 + (j >> 6)]; }
    else if (i < 12288)  { int j = i - 10240; v = W1s[(j & 63) * 32 + (j >> 6)]; }
    else if (i < 12544)  { int j = i - 12288; v = W2s[(j & 31) * 8  + (j >> 5)]; }
    else return;
    o[i] = f2bf(v);
}

// ---------------------------------------------------------------------------
// Block-specialized node+hist kernel. 256 threads/block.
// Node blocks: 4 waves cooperatively process 64 nodes (wave w owns row-tile w).
// Hist blocks: rank-claim atomics, 4 independent edges/thread.
// Interleaved even/odd so both types are co-resident from t=0.
// ---------------------------------------------------------------------------
__global__ __launch_bounds__(256) void node_hist_kernel(
    const float* __restrict__ h,
    const unsigned short* __restrict__ WsT, const float* __restrict__ b_src,
    const unsigned short* __restrict__ WdT, const float* __restrict__ b_dst,
    const unsigned short* __restrict__ W1T, const float* __restrict__ ba1,
    const float* __restrict__ Wa2, const float* __restrict__ ba2,
    unsigned short* __restrict__ g_src_out, unsigned short* __restrict__ g_dst_out,
    float* __restrict__ out,
    const int* __restrict__ edge, const int* __restrict__ flags,
    int* __restrict__ counts, int* __restrict__ rank,
    int nodeB, int histB, int E, int N, int histT)
{
    __shared__ __align__(16) unsigned short sX[64 * XS];  // h rows, later hid
    __shared__ __align__(16) unsigned short sY[64 * XS];  // g rows (raw)
    __shared__ float sW2[NHID * NH];
    __shared__ float sb2[NH];

    int bid = blockIdx.x;
    int mn = nodeB < histB ? nodeB : histB;
    bool isNode; int idx;
    if (bid < 2 * mn) { isNode = !(bid & 1); idx = bid >> 1; }
    else              { idx = bid - 2 * mn + mn; isNode = (nodeB > histB); }

    int tid = threadIdx.x;

    if (!isNode) {
        // ---------------- hist path (proven R15 form) ----------------
        int t = idx * 256 + tid;
        int wide = flags[0];
        #pragma unroll
        for (int k = 0; k < 4; k++) {
            int e = t + k * histT;
            if (e >= E) break;
            int s, d;
            load_edge(edge, e, E, wide, s, d);
            if ((unsigned)s >= (unsigned)N || (unsigned)d >= (unsigned)N) { rank[e] = -1; continue; }
            rank[e] = atomicAdd(&counts[d], 1);
        }
        return;
    }

    // ---------------- node path: 4 waves, 64 nodes ----------------
    int wave = tid >> 6;
    int lane = tid & 63;
    int nsub = lane & 15, quad = lane >> 4;
    int base = idx * 64;

    for (int i = tid; i < NHID * NH; i += 256) sW2[i] = Wa2[i];
    if (tid < NH) sb2[tid] = ba2[tid];

    // stage h rows: thread t handles row t>>2, quarter t&3 (16 floats)
    {
        int row = tid >> 2, part = tid & 3;
        int n = base + row;
        size_t nn = (n < N) ? (size_t)n : (size_t)(N - 1);
        const float4* hv = (const float4*)(h + nn * NF) + part * 4;
        unsigned short* xp = sX + row * XS + part * 16;
        #pragma unroll
        for (int k = 0; k < 2; k++) {
            float4 u0 = hv[2 * k], u1 = hv[2 * k + 1];
            float f[8] = { u0.x, u0.y, u0.z, u0.w, u1.x, u1.y, u1.z, u1.w };
            uint4 p = pack8(f);
            uint2* q = (uint2*)(xp + k * 8);
            q[0] = make_uint2(p.x, p.y);
            q[1] = make_uint2(p.z, p.w);
        }
    }
    __syncthreads();

    #pragma unroll 1
    for (int m = 0; m < 2; m++) {
        const unsigned short* WT = m ? WdT : WsT;
        const float* bb = m ? b_dst : b_src;
        unsigned short* gout = m ? g_dst_out : g_src_out;

        if (m == 1) __syncthreads();   // g_src-store reads of sY done before overwrite

        bf16x8v Bf[2][4];
        #pragma unroll
        for (int ks = 0; ks < 2; ks++)
            #pragma unroll
            for (int nt = 0; nt < 4; nt++) {
                union { uint4 u; bf16x8v v; } u;
                u.u = *(const uint4*)(WT + (nt * 16 + nsub) * 64 + ks * 32 + quad * 8);
                Bf[ks][nt] = u.v;
            }

        f32x4v acc[4];
        #pragma unroll
        for (int nt = 0; nt < 4; nt++) { f32x4v z = {0.f, 0.f, 0.f, 0.f}; acc[nt] = z; }

        #pragma unroll
        for (int ks = 0; ks < 2; ks++) {
            const unsigned short* ap = sX + (wave * 16 + nsub) * XS + ks * 32 + quad * 8;
            union { uint2 d[2]; bf16x8v v; } ua;
            ua.d[0] = *(const uint2*)ap;
            ua.d[1] = *(const uint2*)(ap + 4);
            #pragma unroll
            for (int nt = 0; nt < 4; nt++)
                acc[nt] = __builtin_amdgcn_mfma_f32_16x16x32_bf16(
                    ua.v, Bf[ks][nt], acc[nt], 0, 0, 0);
        }

        // C-layout + bias -> sY rows [16*wave, 16*wave+16)
        #pragma unroll
        for (int nt = 0; nt < 4; nt++) {
            float bv = bb[nt * 16 + nsub];
            #pragma unroll
            for (int r = 0; r < 4; r++)
                sY[(wave * 16 + quad * 4 + r) * XS + nt * 16 + nsub] =
                    f2bf(acc[nt][r] + bv);
        }
        __syncthreads();

        // g store: thread t -> row t>>2, quarter t&3
        {
            int row = tid >> 2, part = tid & 3;
            int n = base + row;
            if (n < N) {
                const unsigned short* yp = sY + row * XS + part * 16;
                uint2 a0 = *(const uint2*)(yp);
                uint2 a1 = *(const uint2*)(yp + 4);
                uint2 a2 = *(const uint2*)(yp + 8);
                uint2 a3 = *(const uint2*)(yp + 12);
                uint4* gp = (uint4*)(gout + (size_t)n * NF + part * 16);
                gp[0] = make_uint4(a0.x, a0.y, a1.x, a1.y);
                gp[1] = make_uint4(a2.x, a2.y, a3.x, a3.y);
            }
        }
    }
    // sY holds raw g_dst rows. (g_dst store reads sY; MLP below also only reads sY.)

    // ---- MLP layer 1 via MFMA: wave w owns row-tile w ----
    bf16x8v B1f[2][2];
    #pragma unroll
    for (int ks = 0; ks < 2; ks++)
        #pragma unroll
        for (int nt = 0; nt < 2; nt++) {
            union { uint4 u; bf16x8v v; } u;
            u.u = *(const uint4*)(W1T + (nt * 16 + nsub) * 64 + ks * 32 + quad * 8);
            B1f[ks][nt] = u.v;
        }

    f32x4v acc2[2];
    #pragma unroll
    for (int nt = 0; nt < 2; nt++) { f32x4v z = {0.f, 0.f, 0.f, 0.f}; acc2[nt] = z; }

    #pragma unroll
    for (int ks = 0; ks < 2; ks++) {
        const unsigned short* ap = sY + (wave * 16 + nsub) * XS + ks * 32 + quad * 8;
        uint2 d0 = *(const uint2*)ap;
        uint2 d1 = *(const uint2*)(ap + 4);
        float f[8];
        unpack8(make_uint4(d0.x, d0.y, d1.x, d1.y), f);
        #pragma unroll
        for (int t = 0; t < 8; t++) f[t] = leaky(f[t]);
        uint4 p = pack8(f);
        union { uint4 u; bf16x8v v; } ua; ua.u = p;
        #pragma unroll
        for (int nt = 0; nt < 2; nt++)
            acc2[nt] = __builtin_amdgcn_mfma_f32_16x16x32_bf16(
                ua.v, B1f[ks][nt], acc2[nt], 0, 0, 0);
    }

    // hid = leaky(acc2 + b1) -> sX rows [16*wave,16*wave+16) cols 0..31
    #pragma unroll
    for (int nt = 0; nt < 2; nt++) {
        float b1v = ba1[nt * 16 + nsub];
        #pragma unroll
        for (int r = 0; r < 4; r++)
            sX[(wave * 16 + quad * 4 + r) * XS + nt * 16 + nsub] =
                f2bf(leaky(acc2[nt][r] + b1v));
    }
    __syncthreads();

    // ---- layer 2 + base term: thread t -> node t>>2, out quarter t&3 ----
    {
        int row = tid >> 2, part = tid & 3;
        int n = base + row;
        if (n < N) {
            float hid[NHID];
            const unsigned short* hrow = sX + row * XS;
            #pragma unroll
            for (int k = 0; k < 8; k++) {
                uint2 dv = *(const uint2*)(hrow + k * 4);
                hid[k * 4 + 0] = bf2f((unsigned short)(dv.x & 0xffffu));
                hid[k * 4 + 1] = bf2f((unsigned short)(dv.x >> 16));
                hid[k * 4 + 2] = bf2f((unsigned short)(dv.y & 0xffffu));
                hid[k * 4 + 3] = bf2f((unsigned short)(dv.y >> 16));
            }
            float a[NH];
            #pragma unroll
            for (int j = 0; j < NH; j++) a[j] = sb2[j];
            #pragma unroll
            for (int k = 0; k < NHID; k++) {
                float xk = hid[k];
                #pragma unroll
                for (int j = 0; j < NH; j++) a[j] = fmaf(xk, sW2[k * NH + j], a[j]);
            }
            float a0 = sigmoidf(a[part * 2]);
            float a1 = sigmoidf(a[part * 2 + 1]);

            const unsigned short* yp = sY + row * XS + part * 16;
            float g[16];
            {
                uint2 u0 = *(const uint2*)(yp);
                uint2 u1 = *(const uint2*)(yp + 4);
                uint2 u2 = *(const uint2*)(yp + 8);
                uint2 u3 = *(const uint2*)(yp + 12);
                unpack8(make_uint4(u0.x, u0.y, u1.x, u1.y), g);
                unpack8(make_uint4(u2.x, u2.y, u3.x, u3.y), g + 8);
            }
            float4* op = (float4*)(out + (size_t)n * NF + part * 16);
            op[0] = make_float4(a0 * g[0],  a0 * g[1],  a0 * g[2],  a0 * g[3]);
            op[1] = make_float4(a0 * g[4],  a0 * g[5],  a0 * g[6],  a0 * g[7]);
            op[2] = make_float4(a1 * g[8],  a1 * g[9],  a1 * g[10], a1 * g[11]);
            op[3] = make_float4(a1 * g[12], a1 * g[13], a1 * g[14], a1 * g[15]);
        }
    }
}

// ---------------------------------------------------------------------------
// Scans (unchanged).
// ---------------------------------------------------------------------------
__global__ __launch_bounds__(256) void scan1_kernel(
    const int* __restrict__ counts, int* __restrict__ offsets,
    int* __restrict__ bsums, int N)
{
    __shared__ int lds[256];
    int tid = threadIdx.x;
    int base = blockIdx.x * 2048 + tid * 8;
    int v[8]; int s = 0;
    #pragma unroll
    for (int k = 0; k < 8; k++) { int idx = base + k; int t = (idx < N) ? counts[idx] : 0; v[k] = t; s += t; }
    lds[tid] = s;
    __syncthreads();
    for (int off = 1; off < 256; off <<= 1) {
        int y = (tid >= off) ? lds[tid - off] : 0;
        __syncthreads();
        lds[tid] += y;
        __syncthreads();
    }
    int run = lds[tid] - s;
    #pragma unroll
    for (int k = 0; k < 8; k++) { int idx = base + k; if (idx < N) offsets[idx] = run; run += v[k]; }
    if (tid == 255) bsums[blockIdx.x] = lds[255];
}

__global__ void scan2_kernel(int* __restrict__ bsums, int* __restrict__ offsets, int NB, int N) {
    if (threadIdx.x == 0 && blockIdx.x == 0) {
        int run = 0;
        for (int i = 0; i < NB; i++) { int t = bsums[i]; bsums[i] = run; run += t; }
        offsets[N] = run;
    }
}

__global__ __launch_bounds__(256) void scan3_kernel(
    int* __restrict__ offsets, const int* __restrict__ bsums, int N)
{
    int add = bsums[blockIdx.x];
    int base = blockIdx.x * 2048 + threadIdx.x * 8;
    #pragma unroll
    for (int k = 0; k < 8; k++) { int idx = base + k; if (idx < N) offsets[idx] += add; }
}

// ---------------------------------------------------------------------------
// Block-specialized scatter + fill_d (overlap scattered stores with coalesced
// run fills).
// ---------------------------------------------------------------------------
__global__ __launch_bounds__(256) void scatter_fill_kernel(
    const int* __restrict__ edge, const int* __restrict__ flags,
    const int* __restrict__ offsets, const int* __restrict__ rank,
    int* __restrict__ sorted_s, int* __restrict__ sorted_d,
    int E, int N, int scatB)
{
    int bid = blockIdx.x;
    int tid = threadIdx.x;
    if (bid < scatB) {
        int e = bid * 256 + tid;
        if (e >= E) return;
        int r = rank[e];
        if (r < 0) return;
        int s, d;
        load_edge(edge, e, E, flags[0], s, d);
        sorted_s[offsets[d] + r] = s;
    } else {
        int d = (bid - scatB) * 256 + tid;
        if (d >= N) return;
        int beg = offsets[d], end = offsets[d + 1];
        for (int i = beg; i < end; i++) sorted_d[i] = d;
    }
}

// ---------------------------------------------------------------------------
// Edge MLP, both layers via MFMA (unchanged from R15 — verified).
// ---------------------------------------------------------------------------
__global__ __launch_bounds__(256) void edge_mlp_mfma_kernel(
    const int* __restrict__ sorted_s, const int* __restrict__ sorted_d,
    const int* __restrict__ total_p,
    const unsigned short* __restrict__ g_src, const unsigned short* __restrict__ g_dst,
    const unsigned short* __restrict__ W1T, const float* __restrict__ ba1,
    const unsigned short* __restrict__ W2T, const float* __restrict__ ba2,
    __half* __restrict__ a_sorted)
{
    __shared__ __align__(16) unsigned short sX[4 * 64 * XS];
    __shared__ __align__(16) __half sOut[4 * 64 * OS];
    __shared__ float sb1[NHID], sb2[NH];

    int tid = threadIdx.x;
    if (tid < NHID) sb1[tid] = ba1[tid];
    if (tid < NH) sb2[tid] = ba2[tid];

    int wave = tid >> 6;
    int lane = tid & 63;
    int nsub = lane & 15;
    int quad = lane >> 4;
    int total = *total_p;
    int i = blockIdx.x * 256 + wave * 64 + lane;
    bool valid = i < total;
    int s = valid ? sorted_s[i] : 0;
    int d = valid ? sorted_d[i] : 0;

    unsigned short* xrow = sX + (wave * 64 + lane) * XS;
    {
        const uint4* gs = (const uint4*)(g_src + (size_t)s * NF);
        const uint4* gd = (const uint4*)(g_dst + (size_t)d * NF);
        #pragma unroll
        for (int k = 0; k < 8; k++) {
            float A8[8], B8[8], x8[8];
            unpack8(gs[k], A8); unpack8(gd[k], B8);
            #pragma unroll
            for (int t = 0; t < 8; t++) x8[t] = leaky(A8[t] + B8[t]);
            uint4 pk = pack8(x8);
            uint2* q = (uint2*)(xrow + k * 8);
            q[0] = make_uint2(pk.x, pk.y);
            q[1] = make_uint2(pk.z, pk.w);
        }
    }

    bf16x8v Bf[2][2];
    #pragma unroll
    for (int ks = 0; ks < 2; ks++)
        #pragma unroll
        for (int nt = 0; nt < 2; nt++) {
            union { uint4 u; bf16x8v v; } u;
            u.u = *(const uint4*)(W1T + (nt * 16 + nsub) * 64 + ks * 32 + quad * 8);
            Bf[ks][nt] = u.v;
        }
    bf16x8v B2f;
    {
        union { uint4 u; bf16x8v v; } u;
        if (nsub < NH) u.u = *(const uint4*)(W2T + nsub * 32 + quad * 8);
        else           u.u = make_uint4(0u, 0u, 0u, 0u);
        B2f = u.v;
    }

    __syncthreads();

    f32x4v acc[4][2];
    #pragma unroll
    for (int mt = 0; mt < 4; mt++)
        #pragma unroll
        for (int nt = 0; nt < 2; nt++) {
            f32x4v z = {0.f, 0.f, 0.f, 0.f};
            acc[mt][nt] = z;
        }

    const unsigned short* wbase = sX + wave * 64 * XS;
    #pragma unroll
    for (int ks = 0; ks < 2; ks++) {
        #pragma unroll
        for (int mt = 0; mt < 4; mt++) {
            const unsigned short* ap = wbase + (mt * 16 + nsub) * XS + ks * 32 + quad * 8;
            union { uint2 d[2]; bf16x8v v; } ua;
            ua.d[0] = *(const uint2*)ap;
            ua.d[1] = *(const uint2*)(ap + 4);
            #pragma unroll
            for (int nt = 0; nt < 2; nt++)
                acc[mt][nt] = __builtin_amdgcn_mfma_f32_16x16x32_bf16(
                    ua.v, Bf[ks][nt], acc[mt][nt], 0, 0, 0);
        }
    }

    __syncthreads();

    #pragma unroll
    for (int nt = 0; nt < 2; nt++) {
        int n = nt * 16 + nsub;
        float b1v = sb1[n];
        #pragma unroll
        for (int mt = 0; mt < 4; mt++) {
            #pragma unroll
            for (int r = 0; r < 4; r++) {
                int m = mt * 16 + quad * 4 + r;
                sX[(wave * 64 + m) * XS + n] = f2bf(leaky(acc[mt][nt][r] + b1v));
            }
        }
    }

    __syncthreads();

    f32x4v acc2[4];
    #pragma unroll
    for (int mt = 0; mt < 4; mt++) { f32x4v z = {0.f, 0.f, 0.f, 0.f}; acc2[mt] = z; }
    #pragma unroll
    for (int mt = 0; mt < 4; mt++) {
        const unsigned short* ap = wbase + (mt * 16 + nsub) * XS + quad * 8;
        union { uint2 d[2]; bf16x8v v; } ua;
        ua.d[0] = *(const uint2*)ap;
        ua.d[1] = *(const uint2*)(ap + 4);
        acc2[mt] = __builtin_amdgcn_mfma_f32_16x16x32_bf16(ua.v, B2f, acc2[mt], 0, 0, 0);
    }

    if (nsub < NH) {
        float b2v = sb2[nsub];
        #pragma unroll
        for (int mt = 0; mt < 4; mt++)
            #pragma unroll
            for (int r = 0; r < 4; r++) {
                int m = mt * 16 + quad * 4 + r;
                sOut[(wave * 64 + m) * OS + nsub] = __float2half(sigmoidf(acc2[mt][r] + b2v));
            }
    }
    __syncthreads();

    if (valid) {
        const unsigned int* orow = (const unsigned int*)(sOut + (wave * 64 + lane) * OS);
        uint4 pk = make_uint4(orow[0], orow[1], orow[2], orow[3]);
        *(uint4*)(a_sorted + (size_t)i * NH) = pk;
    }
}

// ---------------------------------------------------------------------------
// Aggregate v2 (unchanged).
// ---------------------------------------------------------------------------
__global__ __launch_bounds__(256) void aggregate_kernel(
    const int* __restrict__ offsets, const int* __restrict__ sorted_s,
    const __half* __restrict__ a_sorted, const unsigned short* __restrict__ g_src,
    float* __restrict__ out, int N)
{
    int d = blockIdx.x * 32 + (threadIdx.x >> 3);
    if (d >= N) return;
    int l = threadIdx.x & 7;
    int beg = offsets[d], end = offsets[d + 1];

    float acc[8] = {0.f, 0.f, 0.f, 0.f, 0.f, 0.f, 0.f, 0.f};
    int i = beg;
    for (; i + 2 <= end; i += 2) {
        int s0 = sorted_s[i];
        int s1 = sorted_s[i + 1];
        float av0 = __half2float(a_sorted[(size_t)i * NH + l]);
        float av1 = __half2float(a_sorted[(size_t)(i + 1) * NH + l]);
        uint4 q0 = *(const uint4*)(g_src + (size_t)s0 * NF + l * 8);
        uint4 q1 = *(const uint4*)(g_src + (size_t)s1 * NF + l * 8);
        float f0[8], f1[8];
        unpack8(q0, f0); unpack8(q1, f1);
        #pragma unroll
        for (int t = 0; t < 8; t++) acc[t] = fmaf(av0, f0[t], acc[t]);
        #pragma unroll
        for (int t = 0; t < 8; t++) acc[t] = fmaf(av1, f1[t], acc[t]);
    }
    if (i < end) {
        int s0 = sorted_s[i];
        float av0 = __half2float(a_sorted[(size_t)i * NH + l]);
        uint4 q0 = *(const uint4*)(g_src + (size_t)s0 * NF + l * 8);
        float f0[8]; unpack8(q0, f0);
        #pragma unroll
        for (int t = 0; t < 8; t++) acc[t] = fmaf(av0, f0[t], acc[t]);
    }

    float4* o4 = (float4*)(out + (size_t)d * NF + l * 8);
    float4 v0 = o4[0], v1 = o4[1];
    v0.x += acc[0]; v0.y += acc[1]; v0.z += acc[2]; v0.w += acc[3];
    v1.x += acc[4]; v1.y += acc[5]; v1.z += acc[6]; v1.w += acc[7];
    o4[0] = v0; o4[1] = v1;
}

// ---------------------------------------------------------------------------
// Fallbacks (small ws): detect + scalar node + atomic edge kernels.
// ---------------------------------------------------------------------------
__global__ void detect_kernel(const int* __restrict__ edge, int* __restrict__ flags) {
    if (threadIdx.x == 0 && blockIdx.x == 0) {
        int oddnz = 0;
        for (int i = 0; i < 32; i++) oddnz |= edge[2 * i + 1];
        flags[0] = (oddnz == 0) ? 1 : 0;
    }
}

template <bool STORE_G>
__global__ __launch_bounds__(256) void node_kernel_t(
    const float* __restrict__ h,
    const float* __restrict__ W_src, const float* __restrict__ b_src,
    const float* __restrict__ W_dst, const float* __restrict__ b_dst,
    const float* __restrict__ Wa1, const float* __restrict__ ba1,
    const float* __restrict__ Wa2, const float* __restrict__ ba2,
    unsigned short* __restrict__ g_src_out, unsigned short* __restrict__ g_dst_out,
    float* __restrict__ out, int N)
{
    __shared__ __align__(16) float sWs[NF * NF];
    __shared__ __align__(16) float sWd[NF * NF];
    __shared__ __align__(16) float sW1[NF * NHID];
    __shared__ __align__(16) float sW2[NHID * NH];
    __shared__ float sbs[NF], sbd[NF], sb1[NHID], sb2[NH];

    int tid = threadIdx.x;
    for (int i = tid; i < NF * NF; i += 256) { sWs[i] = W_src[i]; sWd[i] = W_dst[i]; }
    for (int i = tid; i < NF * NHID; i += 256) sW1[i] = Wa1[i];
    if (tid < NHID * NH) sW2[tid] = Wa2[tid];
    if (tid < NF) { sbs[tid] = b_src[tid]; sbd[tid] = b_dst[tid]; }
    if (tid < NHID) sb1[tid] = ba1[tid];
    if (tid < NH) sb2[tid] = ba2[tid];
    __syncthreads();

    int n = blockIdx.x * 256 + tid;
    if (n >= N) return;

    float hrow[NF];
    const float4* hv = (const float4*)(h + (size_t)n * NF);
    #pragma unroll
    for (int k = 0; k < 16; k++) {
        float4 u = hv[k];
        hrow[k * 4 + 0] = u.x; hrow[k * 4 + 1] = u.y;
        hrow[k * 4 + 2] = u.z; hrow[k * 4 + 3] = u.w;
    }

    float acc[NF];
    const float4* Wsv = (const float4*)sWs;
    const float4* Wdv = (const float4*)sWd;

    if (STORE_G) {
        #pragma unroll
        for (int j = 0; j < NF; j++) acc[j] = sbs[j];
        for (int i = 0; i < NF; i++) {
            float hi = hrow[i];
            #pragma unroll
            for (int jb = 0; jb < 16; jb++) {
                float4 w = Wsv[i * 16 + jb];
                acc[jb * 4 + 0] = fmaf(hi, w.x, acc[jb * 4 + 0]);
                acc[jb * 4 + 1] = fmaf(hi, w.y, acc[jb * 4 + 1]);
                acc[jb * 4 + 2] = fmaf(hi, w.z, acc[jb * 4 + 2]);
                acc[jb * 4 + 3] = fmaf(hi, w.w, acc[jb * 4 + 3]);
            }
        }
        uint4* gs = (uint4*)(g_src_out + (size_t)n * NF);
        #pragma unroll
        for (int k = 0; k < 8; k++) gs[k] = pack8(acc + k * 8);
    }

    #pragma unroll
    for (int j = 0; j < NF; j++) acc[j] = sbd[j];
    for (int i = 0; i < NF; i++) {
        float hi = hrow[i];
        #pragma unroll
        for (int jb = 0; jb < 16; jb++) {
            float4 w = Wdv[i * 16 + jb];
            acc[jb * 4 + 0] = fmaf(hi, w.x, acc[jb * 4 + 0]);
            acc[jb * 4 + 1] = fmaf(hi, w.y, acc[jb * 4 + 1]);
            acc[jb * 4 + 2] = fmaf(hi, w.z, acc[jb * 4 + 2]);
            acc[jb * 4 + 3] = fmaf(hi, w.w, acc[jb * 4 + 3]);
        }
    }
    if (STORE_G) {
        uint4* gd = (uint4*)(g_dst_out + (size_t)n * NF);
        #pragma unroll
        for (int k = 0; k < 8; k++) gd[k] = pack8(acc + k * 8);
    }

    float hid[NHID];
    #pragma unroll
    for (int j = 0; j < NHID; j++) hid[j] = sb1[j];
    const float4* W1v = (const float4*)sW1;
    for (int i = 0; i < NF; i++) {
        float xi = leaky(acc[i]);
        #pragma unroll
        for (int jb = 0; jb < 8; jb++) {
            float4 w = W1v[i * 8 + jb];
            hid[jb * 4 + 0] = fmaf(xi, w.x, hid[jb * 4 + 0]);
            hid[jb * 4 + 1] = fmaf(xi, w.y, hid[jb * 4 + 1]);
            hid[jb * 4 + 2] = fmaf(xi, w.z, hid[jb * 4 + 2]);
            hid[jb * 4 + 3] = fmaf(xi, w.w, hid[jb * 4 + 3]);
        }
    }
    float a[NH];
    #pragma unroll
    for (int j = 0; j < NH; j++) a[j] = sb2[j];
    #pragma unroll
    for (int k = 0; k < NHID; k++) {
        float xk = leaky(hid[k]);
        #pragma unroll
        for (int j = 0; j < NH; j++) a[j] = fmaf(xk, sW2[k * NH + j], a[j]);
    }
    #pragma unroll
    for (int j = 0; j < NH; j++) a[j] = sigmoidf(a[j]);

    float4* ap = (float4*)(out + (size_t)n * NF);
    #pragma unroll
    for (int k = 0; k < 16; k++) {
        int j = k * 4;
        ap[k] = make_float4(a[(j + 0) >> 3] * acc[j + 0],
                            a[(j + 1) >> 3] * acc[j + 1],
                            a[(j + 2) >> 3] * acc[j + 2],
                            a[(j + 3) >> 3] * acc[j + 3]);
    }
}

__global__ __launch_bounds__(256) void edge_kernel(
    const int* __restrict__ edge, const int* __restrict__ flags,
    const unsigned short* __restrict__ g_src, const unsigned short* __restrict__ g_dst,
    const float* __restrict__ Wa1, const float* __restrict__ ba1,
    const float* __restrict__ Wa2, const float* __restrict__ ba2,
    float* __restrict__ out, int E, int N)
{
    __shared__ __align__(16) float sW1[NF * NHID];
    __shared__ __align__(16) float sW2[NHID * NH];
    __shared__ float sb1[NHID], sb2[NH];
    int tid = threadIdx.x;
    for (int i = tid; i < NF * NHID; i += 256) sW1[i] = Wa1[i];
    if (tid < NHID * NH) sW2[tid] = Wa2[tid];
    if (tid < NHID) sb1[tid] = ba1[tid];
    if (tid < NH) sb2[tid] = ba2[tid];
    __syncthreads();

    int e = blockIdx.x * 256 + tid;
    if (e >= E) return;
    int s, d;
    load_edge(edge, e, E, flags[0], s, d);
    if ((unsigned)s >= (unsigned)N || (unsigned)d >= (unsigned)N) return;

    float ms[NF];
    float hid[NHID];
    #pragma unroll
    for (int j = 0; j < NHID; j++) hid[j] = sb1[j];

    const uint4* gs = (const uint4*)(g_src + (size_t)s * NF);
    const uint4* gd = (const uint4*)(g_dst + (size_t)d * NF);
    #pragma unroll
    for (int k = 0; k < 8; k++) {
        float a8[8], b8[8];
        unpack8(gs[k], a8);
        unpack8(gd[k], b8);
        #pragma unroll
        for (int t = 0; t < 8; t++) {
            int i = k * 8 + t;
            ms[i] = a8[t];
            float x = leaky(a8[t] + b8[t]);
            #pragma unroll
            for (int j = 0; j < NHID; j++) hid[j] = fmaf(x, sW1[i * NHID + j], hid[j]);
        }
    }

    float a[NH];
    #pragma unroll
    for (int j = 0; j < NH; j++) a[j] = sb2[j];
    #pragma unroll
    for (int k = 0; k < NHID; k++) {
        float xk = leaky(hid[k]);
        #pragma unroll
        for (int j = 0; j < NH; j++) a[j] = fmaf(xk, sW2[k * NH + j], a[j]);
    }

    float* arow = out + (size_t)d * NF;
    #pragma unroll
    for (int hh = 0; hh < NH; hh++) {
        float ah = sigmoidf(a[hh]);
        #pragma unroll
        for (int dd = 0; dd < ND; dd++)
            unsafeAtomicAdd(arow + hh * ND + dd, ah * ms[hh * ND + dd]);
    }
}

__global__ __launch_bounds__(256) void edge_kernel_fused(
    const int* __restrict__ edge, const int* __restrict__ flags,
    const float* __restrict__ h,
    const float* __restrict__ W_src, const float* __restrict__ b_src,
    const float* __restrict__ W_dst, const float* __restrict__ b_dst,
    const float* __restrict__ Wa1, const float* __restrict__ ba1,
    const float* __restrict__ Wa2, const float* __restrict__ ba2,
    float* __restrict__ out, int E, int N)
{
    __shared__ __align__(16) float sWs[NF * NF];
    __shared__ __align__(16) float sWd[NF * NF];
    __shared__ __align__(16) float sW1[NF * NHID];
    __shared__ __align__(16) float sW2[NHID * NH];
    __shared__ float sbs[NF], sbd[NF], sb1[NHID], sb2[NH];
    int tid = threadIdx.x;
    for (int i = tid; i < NF * NF; i += 256) { sWs[i] = W_src[i]; sWd[i] = W_dst[i]; }
    for (int i = tid; i < NF * NHID; i += 256) sW1[i] = Wa1[i];
    if (tid < NHID * NH) sW2[tid] = Wa2[tid];
    if (tid < NF) { sbs[tid] = b_src[tid]; sbd[tid] = b_dst[tid]; }
    if (tid < NHID) sb1[tid] = ba1[tid];
    if (tid < NH) sb2[tid] = ba2[tid];
    __syncthreads();

    int e = blockIdx.x * 256 + tid;
    if (e >= E) return;
    int wide = flags ? flags[0] : 0;
    int s, d;
    load_edge(edge, e, E, wide, s, d);
    if ((unsigned)s >= (unsigned)N || (unsigned)d >= (unsigned)N) return;

    float gsr[NF], msg[NF];
    {
        float hrow[NF];
        #pragma unroll
        for (int i = 0; i < NF; i++) hrow[i] = h[(size_t)s * NF + i];
        #pragma unroll
        for (int j = 0; j < NF; j++) gsr[j] = sbs[j];
        for (int i = 0; i < NF; i++) {
            float hi = hrow[i];
            #pragma unroll
            for (int j = 0; j < NF; j++) gsr[j] = fmaf(hi, sWs[i * NF + j], gsr[j]);
        }
    }
    #pragma unroll
    for (int j = 0; j < NF; j++) msg[j] = gsr[j] + sbd[j];
    for (int i = 0; i < NF; i++) {
        float hi = h[(size_t)d * NF + i];
        #pragma unroll
        for (int j = 0; j < NF; j++) msg[j] = fmaf(hi, sWd[i * NF + j], msg[j]);
    }

    float hid[NHID];
    #pragma unroll
    for (int j = 0; j < NHID; j++) hid[j] = sb1[j];
    for (int i = 0; i < NF; i++) {
        float x = leaky(msg[i]);
        #pragma unroll
        for (int j = 0; j < NHID; j++) hid[j] = fmaf(x, sW1[i * NHID + j], hid[j]);
    }
    float a[NH];
    #pragma unroll
    for (int j = 0; j < NH; j++) a[j] = sb2[j];
    #pragma unroll
    for (int k = 0; k < NHID; k++) {
        float xk = leaky(hid[k]);
        #pragma unroll
        for (int j = 0; j < NH; j++) a[j] = fmaf(xk, sW2[k * NH + j], a[j]);
    }

    float* arow = out + (size_t)d * NF;
    #pragma unroll
    for (int hh = 0; hh < NH; hh++) {
        float ah = sigmoidf(a[hh]);
        #pragma unroll
        for (int dd = 0; dd < ND; dd++)
            unsafeAtomicAdd(arow + hh * ND + dd, ah * gsr[hh * ND + dd]);
    }
}

static inline size_t al256(size_t x) { return (x + 255) & ~(size_t)255; }

extern "C" void kernel_launch(void* const* d_in, const int* in_sizes, int n_in,
                              void* d_out, int out_size, void* d_ws, size_t ws_size,
                              hipStream_t stream) {
    const float* h       = (const float*)d_in[0];
    const float* W_src   = (const float*)d_in[1];
    const float* b_src   = (const float*)d_in[2];
    const float* W_dst   = (const float*)d_in[3];
    const float* b_dst   = (const float*)d_in[4];
    const float* Wa1_src = (const float*)d_in[5];
    const float* ba1_src = (const float*)d_in[6];
    const float* Wa2_src = (const float*)d_in[7];
    const float* ba2_src = (const float*)d_in[8];
    const float* Wa1_dst = (const float*)d_in[9];
    const float* ba1_dst = (const float*)d_in[10];
    const float* Wa2_dst = (const float*)d_in[11];
    const float* ba2_dst = (const float*)d_in[12];
    const int* edge = (const int*)d_in[13];

    int N = in_sizes[0] / NF;
    int E = in_sizes[13] / 2;
    float* out = (float*)d_out;

    int nodeBlocks = (N + 255) / 256;
    int nodeB = (N + 63) / 64;
    int edgeBlocks = (E + 255) / 256;
    int NB1 = (N + 2047) / 2048;
    int prepN = (N > WBF_TOTAL ? N : WBF_TOTAL);
    int histB = (E + 1023) / 1024;
    int histT = histB * 256;

    size_t o_flags  = 0;
    size_t o_wbf    = al256(o_flags + 256);
    size_t o_gsrc   = al256(o_wbf + (size_t)WBF_TOTAL * 2);
    size_t o_gdst   = al256(o_gsrc + (size_t)N * NF * 2);
    size_t o_asort  = al256(o_gdst + (size_t)N * NF * 2);   // E*NH*2 bytes; first E*4 aliased as rank[]
    size_t o_counts = al256(o_asort + (size_t)E * NH * 2);
    size_t o_offs   = al256(o_counts + (size_t)N * 4);
    size_t o_bsums  = al256(o_offs + ((size_t)N + 1) * 4);
    size_t o_sorted = al256(o_bsums + (size_t)NB1 * 4);     // E*4 sorted_s + E*4 sorted_d
    size_t need     = o_sorted + (size_t)E * 8;

    size_t gB = (size_t)N * NF * 2;

    if (ws_size >= need) {
        char* w = (char*)d_ws;
        int*            flags   = (int*)(w + o_flags);
        unsigned short* wbf     = (unsigned short*)(w + o_wbf);
        unsigned short* WsT     = wbf;
        unsigned short* WdT     = wbf + 4096;
        unsigned short* W1dT    = wbf + 8192;
        unsigned short* W1sT    = wbf + 10240;
        unsigned short* W2sT    = wbf + 12288;
        unsigned short* g_src   = (unsigned short*)(w + o_gsrc);
        unsigned short* g_dst   = (unsigned short*)(w + o_gdst);
        __half*         a_sort  = (__half*)(w + o_asort);
        int*            rank    = (int*)(w + o_asort);
        int*            counts  = (int*)(w + o_counts);
        int*            offsets = (int*)(w + o_offs);
        int*            bsums   = (int*)(w + o_bsums);
        int*            sorted_s = (int*)(w + o_sorted);
        int*            sorted_d = sorted_s + E;

        prep_weights_kernel<<<(prepN + 255) / 256, 256, 0, stream>>>(
            W_src, W_dst, Wa1_dst, Wa1_src, Wa2_src, wbf, counts, N, edge, flags);

        node_hist_kernel<<<nodeB + histB, 256, 0, stream>>>(
            h, WsT, b_src, WdT, b_dst,
            W1dT, ba1_dst, Wa2_dst, ba2_dst,
            g_src, g_dst, out,
            edge, flags, counts, rank,
            nodeB, histB, E, N, histT);

        scan1_kernel<<<NB1, 256, 0, stream>>>(counts, offsets, bsums, N);
        scan2_kernel<<<1, 1, 0, stream>>>(bsums, offsets, NB1, N);
        scan3_kernel<<<NB1, 256, 0, stream>>>(offsets, bsums, N);

        scatter_fill_kernel<<<edgeBlocks + nodeBlocks, 256, 0, stream>>>(
            edge, flags, offsets, rank, sorted_s, sorted_d, E, N, edgeBlocks);

        edge_mlp_mfma_kernel<<<edgeBlocks, 256, 0, stream>>>(
            sorted_s, sorted_d, offsets + N, g_src, g_dst,
            W1sT, ba1_src, W2sT, ba2_src, a_sort);

        aggregate_kernel<<<(N + 31) / 32, 256, 0, stream>>>(
            offsets, sorted_s, a_sort, g_src, out, N);
    } else if (ws_size >= 256 + 2 * gB) {
        int* flags = (int*)d_ws;
        unsigned short* g_src = (unsigned short*)((char*)d_ws + 256);
        unsigned short* g_dst = g_src + (size_t)N * NF;

        detect_kernel<<<1, 1, 0, stream>>>(edge, flags);

        node_kernel_t<true><<<nodeBlocks, 256, 0, stream>>>(
            h, W_src, b_src, W_dst, b_dst,
            Wa1_dst, ba1_dst, Wa2_dst, ba2_dst,
            g_src, g_dst, out, N);

        edge_kernel<<<edgeBlocks, 256, 0, stream>>>(
            edge, flags, g_src, g_dst,
            Wa1_src, ba1_src, Wa2_src, ba2_src,
            out, E, N);
    } else {
        int* flags = (ws_size >= 256) ? (int*)d_ws : nullptr;
        if (flags) detect_kernel<<<1, 1, 0, stream>>>(edge, flags);

        node_kernel_t<false><<<nodeBlocks, 256, 0, stream>>>(
            h, W_src, b_src, W_dst, b_dst,
            Wa1_dst, ba1_dst, Wa2_dst, ba2_dst,
            nullptr, nullptr, out, N);

        edge_kernel_fused<<<edgeBlocks, 256, 0, stream>>>(
            edge, flags, h,
            W_src, b_src, W_dst, b_dst,
            Wa1_src, ba1_src, Wa2_src, ba2_src,
            out, E, N);
    }
}